// Round 13
// baseline (196.208 us; speedup 1.0000x reference)
//
#include <hip/hip_runtime.h>
#include <math.h>

// Problem constants
constexpr int B  = 2;
constexpr int L  = 4096;
constexpr int C  = 256;
constexpr int H  = 8;
constexpr int D  = 32;          // head dim
constexpr int M  = B * L;       // 8192 rows
constexpr int BH = B * H;       // 16
constexpr int KSPLIT = 8;       // one key-split per XCD; 8 blocks/CU
constexpr int NQT = BH * L;     // 65536
constexpr float LOG2E = 1.4426950408889634f;

typedef short    s8 __attribute__((ext_vector_type(8)));   // 8 bf16
typedef _Float16 h8 __attribute__((ext_vector_type(8)));   // 8 fp16
typedef __fp16   hp2 __attribute__((ext_vector_type(2)));  // cvt_pkrtz native type
typedef float    f4 __attribute__((ext_vector_type(4)));   // MFMA C/D
typedef float    f2 __attribute__((ext_vector_type(2)));   // packed-f32 math

__device__ __forceinline__ unsigned short f2bf(float x) {
    unsigned u = __float_as_uint(x);
    u += 0x7fffu + ((u >> 16) & 1u);      // RNE
    return (unsigned short)(u >> 16);
}
__device__ __forceinline__ float bf2f(unsigned short h) {
    return __uint_as_float(((unsigned)h) << 16);
}
__device__ __forceinline__ unsigned pkrtz(float a, float b) {
    union { hp2 h; unsigned u; } c;
    c.h = __builtin_amdgcn_cvt_pkrtz(a, b);   // v_cvt_pkrtz_f16_f32
    return c.u;
}
__device__ __forceinline__ unsigned short f2h(float x) {
    union { _Float16 h; unsigned short u; } c; c.h = (_Float16)x; return c.u;  // RNE
}
__device__ __forceinline__ float h2f(unsigned short u) {
    union { _Float16 h; unsigned short u; } c; c.u = u; return (float)c.h;
}

// ---------------------------------------------------------------------------
// MERGED prep: split x,y into bf16 hi/lo (blocks 0..2047) AND transpose+split
// the 3 weight matrices (blocks 2048..3071). One dispatch.
// ---------------------------------------------------------------------------
__global__ __launch_bounds__(256) void prep_all(
    const float* __restrict__ x, const float* __restrict__ y,
    const float* __restrict__ Wq, const float* __restrict__ Wkv, const float* __restrict__ Wo,
    unsigned short* __restrict__ xh, unsigned short* __restrict__ xl,
    unsigned short* __restrict__ yh, unsigned short* __restrict__ yl,
    unsigned short* __restrict__ Wqt_h, unsigned short* __restrict__ Wqt_l,
    unsigned short* __restrict__ Wkvt_h, unsigned short* __restrict__ Wkvt_l,
    unsigned short* __restrict__ Wot_h, unsigned short* __restrict__ Wot_l) {
    const int bx = blockIdx.x, tid = threadIdx.x;
    if (bx < 2048) {
        const int idx = bx * 256 + tid;                 // 0..524287
        const float* in; unsigned short *oh, *ol; int i;
        if (idx < M * C / 8) { in = x; oh = xh; ol = xl; i = idx; }
        else                 { in = y; oh = yh; ol = yl; i = idx - M * C / 8; }
        float v[8];
        *reinterpret_cast<float4*>(&v[0]) = *reinterpret_cast<const float4*>(in + (size_t)i * 8);
        *reinterpret_cast<float4*>(&v[4]) = *reinterpret_cast<const float4*>(in + (size_t)i * 8 + 4);
        unsigned short hs[8], lo[8];
        #pragma unroll
        for (int j = 0; j < 8; ++j) {
            hs[j] = f2bf(v[j]);
            lo[j] = f2bf(v[j] - bf2f(hs[j]));
        }
        *reinterpret_cast<uint4*>(oh + (size_t)i * 8) = *reinterpret_cast<uint4*>(hs);
        *reinterpret_cast<uint4*>(ol + (size_t)i * 8) = *reinterpret_cast<uint4*>(lo);
    } else {
        const int t = (bx - 2048) * 256 + tid;          // 0..262143
        const float* W; unsigned short *Oh, *Ol; int nlog2, idx;
        if (t < 65536)       { W = Wq;  Oh = Wqt_h;  Ol = Wqt_l;  nlog2 = 8; idx = t; }
        else if (t < 196608) { W = Wkv; Oh = Wkvt_h; Ol = Wkvt_l; nlog2 = 9; idx = t - 65536; }
        else                 { W = Wo;  Oh = Wot_h;  Ol = Wot_l;  nlog2 = 8; idx = t - 196608; }
        const int NN = 1 << nlog2;
        const int n = idx & (NN - 1);
        const int k = idx >> nlog2;
        const float w = W[(size_t)k * NN + n];
        const unsigned short h = f2bf(w);
        Oh[(size_t)n * 256 + k] = h;
        Ol[(size_t)n * 256 + k] = f2bf(w - bf2f(h));
    }
}

// ---------------------------------------------------------------------------
// MERGED projection: q (by 0..3), k (by 4..7), v (by 8..11).
// q/k: fused l2-norm epilogue -> fp16 qf/kf [bh][l][32].  NOTE: q scale is
// temp[h] only (natural-log exponent; poly-exp in attn computes e^s).
// v:   fused transpose+perm epilogue -> fp16 vT[bh][d][slot] directly.
// ---------------------------------------------------------------------------
__global__ __launch_bounds__(256) void gemm_proj(
    const unsigned short* __restrict__ xh, const unsigned short* __restrict__ xl,
    const unsigned short* __restrict__ yh, const unsigned short* __restrict__ yl,
    const unsigned short* __restrict__ Wqt_h, const unsigned short* __restrict__ Wqt_l,
    const unsigned short* __restrict__ Wkvt_h, const unsigned short* __restrict__ Wkvt_l,
    const float* __restrict__ temp,
    unsigned short* __restrict__ qf, unsigned short* __restrict__ kf,
    unsigned short* __restrict__ vT) {
    __shared__ unsigned short lt[64][68];   // v-transpose buffer (8.5KB)
    const int tid  = threadIdx.x;
    const int wv   = tid >> 6;
    const int lane = tid & 63;
    const int col  = lane & 15;
    const int grp  = lane >> 4;
    const int by   = blockIdx.y;
    const bool isq   = (by < 4);
    const bool blk_v = (by >= 8);
    const unsigned short* Ah = isq ? xh : yh;
    const unsigned short* Al = isq ? xl : yl;
    const unsigned short* Wh = isq ? Wqt_h : Wkvt_h;
    const unsigned short* Wl = isq ? Wqt_l : Wkvt_l;
    const int m_blk  = blockIdx.x * 64;
    const int m_base = m_blk + (wv >> 1) * 32;
    const int n_gl   = (isq ? by : by - 4) * 64 + (wv & 1) * 32;  // col in W-space

    const f4 fz = {0.f, 0.f, 0.f, 0.f};
    f4 acc[2][2] = {{fz, fz}, {fz, fz}};

    const size_t a0 = (size_t)(m_base + col) * 256;
    const size_t w0 = (size_t)(n_gl + col) * 256;

    #pragma unroll
    for (int k0 = 0; k0 < 256; k0 += 32) {
        const int ko = k0 + grp * 8;
        s8 ah[2], al[2], wh[2], wl[2];
        #pragma unroll
        for (int mt = 0; mt < 2; ++mt) {
            ah[mt] = *reinterpret_cast<const s8*>(Ah + a0 + (size_t)mt * 16 * 256 + ko);
            al[mt] = *reinterpret_cast<const s8*>(Al + a0 + (size_t)mt * 16 * 256 + ko);
        }
        #pragma unroll
        for (int nt = 0; nt < 2; ++nt) {
            wh[nt] = *reinterpret_cast<const s8*>(Wh + w0 + (size_t)nt * 16 * 256 + ko);
            wl[nt] = *reinterpret_cast<const s8*>(Wl + w0 + (size_t)nt * 16 * 256 + ko);
        }
        #pragma unroll
        for (int mt = 0; mt < 2; ++mt)
            #pragma unroll
            for (int nt = 0; nt < 2; ++nt) {
                acc[mt][nt] = __builtin_amdgcn_mfma_f32_16x16x32_bf16(ah[mt], wh[nt], acc[mt][nt], 0, 0, 0);
                acc[mt][nt] = __builtin_amdgcn_mfma_f32_16x16x32_bf16(al[mt], wh[nt], acc[mt][nt], 0, 0, 0);
                acc[mt][nt] = __builtin_amdgcn_mfma_f32_16x16x32_bf16(ah[mt], wl[nt], acc[mt][nt], 0, 0, 0);
            }
    }

    if (blk_v) {
        // ---- V path: stage 64x64 tile in LDS, then write vT with slot perm
        #pragma unroll
        for (int mt = 0; mt < 2; ++mt)
            #pragma unroll
            for (int nt = 0; nt < 2; ++nt)
                #pragma unroll
                for (int r = 0; r < 4; ++r)
                    lt[(wv >> 1) * 32 + mt * 16 + grp * 4 + r]
                      [(wv & 1) * 32 + nt * 16 + col] = f2h(acc[mt][nt][r]);
        __syncthreads();
        const int dl  = tid & 63;             // d-col within block (0..63)
        const int q4  = tid >> 6;             // 16-key group (0..3)
        const int dgl = (by - 8) * 64 + dl;   // V d-space 0..255
        const int h   = (dgl >> 5) & 7;
        const int dh  = dgl & 31;
        const int b   = m_blk >> 12;
        const int l0  = m_blk & 4095;
        unsigned ow[8];
        #pragma unroll
        for (int i2 = 0; i2 < 8; ++i2) {
            unsigned lohi[2];
            #pragma unroll
            for (int e = 0; e < 2; ++e) {
                const int s  = q4 * 16 + i2 * 2 + e;     // slot within 64 keys
                const int ch = s >> 5;                    // 32-key chunk (0/1)
                const int ws = s & 31;
                const int kl = ch * 32 + ((ws >> 3) << 2) + (((ws & 7) >> 2) << 4) + (ws & 3);
                lohi[e] = lt[kl][dl];
            }
            ow[i2] = lohi[0] | (lohi[1] << 16);
        }
        unsigned short* dst = vT + ((size_t)((b * H + h) * D + dh)) * L + l0 + q4 * 16;
        uint4 u0 = {ow[0], ow[1], ow[2], ow[3]};
        uint4 u1 = {ow[4], ow[5], ow[6], ow[7]};
        *reinterpret_cast<uint4*>(dst)     = u0;
        *reinterpret_cast<uint4*>(dst + 8) = u1;
        return;
    }

    // ---- q/k path: fused l2-norm epilogue
    const int  h  = (n_gl >> 5) & 7;
    const float tl = isq ? temp[h] : 1.0f;    // natural-log units (no LOG2E)
    unsigned short* dst = isq ? qf : kf;

    #pragma unroll
    for (int mt = 0; mt < 2; ++mt)
        #pragma unroll
        for (int r = 0; r < 4; ++r) {
            float t = acc[mt][0][r] * acc[mt][0][r] + acc[mt][1][r] * acc[mt][1][r];
            t += __shfl_xor(t, 1);
            t += __shfl_xor(t, 2);
            t += __shfl_xor(t, 4);
            t += __shfl_xor(t, 8);
            const float scale = tl / fmaxf(sqrtf(t), 1e-12f);
            const int row = m_base + mt * 16 + grp * 4 + r;
            const int bb = row >> 12, l = row & 4095;
            const size_t base = ((size_t)(bb * H + h) * L + l) * D;
            dst[base + col]      = f2h(acc[mt][0][r] * scale);
            dst[base + 16 + col] = f2h(acc[mt][1][r] * scale);
        }
}

// ---------------------------------------------------------------------------
// Plain register-only bf16-split MFMA GEMM (output projection), fp32 out.
// ---------------------------------------------------------------------------
__global__ __launch_bounds__(256) void gemm_mfma(
    const unsigned short* __restrict__ Ah, const unsigned short* __restrict__ Al,
    const unsigned short* __restrict__ Wth, const unsigned short* __restrict__ Wtl,
    float* __restrict__ out, int N) {
    const int tid  = threadIdx.x;
    const int wv   = tid >> 6;
    const int lane = tid & 63;
    const int col  = lane & 15;
    const int grp  = lane >> 4;
    const int m_base = blockIdx.x * 64 + (wv >> 1) * 32;
    const int n_base = blockIdx.y * 64 + (wv & 1) * 32;

    const f4 fz = {0.f, 0.f, 0.f, 0.f};
    f4 acc[2][2] = {{fz, fz}, {fz, fz}};

    const size_t a0 = (size_t)(m_base + col) * 256;
    const size_t w0 = (size_t)(n_base + col) * 256;

    #pragma unroll
    for (int k0 = 0; k0 < 256; k0 += 32) {
        const int ko = k0 + grp * 8;
        s8 ah[2], al[2], wh[2], wl[2];
        #pragma unroll
        for (int mt = 0; mt < 2; ++mt) {
            ah[mt] = *reinterpret_cast<const s8*>(Ah + a0 + (size_t)mt * 16 * 256 + ko);
            al[mt] = *reinterpret_cast<const s8*>(Al + a0 + (size_t)mt * 16 * 256 + ko);
        }
        #pragma unroll
        for (int nt = 0; nt < 2; ++nt) {
            wh[nt] = *reinterpret_cast<const s8*>(Wth + w0 + (size_t)nt * 16 * 256 + ko);
            wl[nt] = *reinterpret_cast<const s8*>(Wtl + w0 + (size_t)nt * 16 * 256 + ko);
        }
        #pragma unroll
        for (int mt = 0; mt < 2; ++mt)
            #pragma unroll
            for (int nt = 0; nt < 2; ++nt) {
                acc[mt][nt] = __builtin_amdgcn_mfma_f32_16x16x32_bf16(ah[mt], wh[nt], acc[mt][nt], 0, 0, 0);
                acc[mt][nt] = __builtin_amdgcn_mfma_f32_16x16x32_bf16(al[mt], wh[nt], acc[mt][nt], 0, 0, 0);
                acc[mt][nt] = __builtin_amdgcn_mfma_f32_16x16x32_bf16(ah[mt], wl[nt], acc[mt][nt], 0, 0, 0);
            }
    }

    #pragma unroll
    for (int mt = 0; mt < 2; ++mt)
        #pragma unroll
        for (int nt = 0; nt < 2; ++nt)
            #pragma unroll
            for (int r = 0; r < 4; ++r)
                out[(size_t)(m_base + mt * 16 + grp * 4 + r) * N + n_base + nt * 16 + col] =
                    acc[mt][nt][r];
}

// ---------------------------------------------------------------------------
// fp16 MFMA flash attention, swapped-operand QK^T, register-resident P.
// 4 q-tiles/wave, KSPLIT=8, XCD swizzle (as r12).
// NEW: p = e^s via degree-6 Taylor Horner on packed float2 (full-rate FMA
// instead of quarter-rate v_exp_f32); |s| <= |temp|*(1+eps) <= 1.05 for the
// fast path, block-uniform fallback to exp2(s*LOG2E) otherwise.
// ---------------------------------------------------------------------------
#define LOADKV(KB0, KB1, VB0, VB1, KIDX) do {                               \
    const size_t ko_ = kbase + (size_t)((KIDX) + col) * D + grp * 8;        \
    KB0 = *reinterpret_cast<const h8*>(kf + ko_);                           \
    KB1 = *reinterpret_cast<const h8*>(kf + ko_ + 16 * D);                  \
    const size_t vo_ = kbase + (size_t)col * L + (KIDX) + grp * 8;          \
    VB0 = *reinterpret_cast<const h8*>(vT + vo_);                           \
    VB1 = *reinterpret_cast<const h8*>(vT + vo_ + 16 * L);                  \
} while (0)

// degree-6 Taylor of e^x, Horner; valid |x| <= ~1.05 (rel err <= 2.8e-4)
#define EXP_POLY(PDST, S0, S1) do {                                         \
    _Pragma("unroll")                                                       \
    for (int r = 0; r < 4; ++r) {                                           \
        f2 xx = {(S0)[r], (S1)[r]};                                         \
        f2 tt = xx * (1.0f/720.0f) + (1.0f/120.0f);                         \
        tt = tt * xx + (1.0f/24.0f);                                        \
        tt = tt * xx + (1.0f/6.0f);                                         \
        tt = tt * xx + 0.5f;                                                \
        tt = tt * xx + 1.0f;                                                \
        tt = tt * xx + 1.0f;                                                \
        (PDST)[r] = tt.x; (PDST)[r + 4] = tt.y;                             \
    }                                                                       \
} while (0)

#define EXP_HW(PDST, S0, S1) do {                                           \
    _Pragma("unroll")                                                       \
    for (int r = 0; r < 4; ++r) {                                           \
        (PDST)[r]     = __builtin_amdgcn_exp2f((S0)[r] * LOG2E);            \
        (PDST)[r + 4] = __builtin_amdgcn_exp2f((S1)[r] * LOG2E);            \
    }                                                                       \
} while (0)

#define CHUNK(KB0, KB1, VB0, VB1, EXPM) do {                                \
    _Pragma("unroll")                                                       \
    for (int qt = 0; qt < 4; ++qt) {                                        \
        f4 s0 = __builtin_amdgcn_mfma_f32_16x16x32_f16(KB0, qa[qt], fz, 0, 0, 0); \
        f4 s1 = __builtin_amdgcn_mfma_f32_16x16x32_f16(KB1, qa[qt], fz, 0, 0, 0); \
        float p[8];                                                         \
        EXPM(p, s0, s1);                                                    \
        ls[qt] += ((p[0] + p[1]) + (p[2] + p[3])) + ((p[4] + p[5]) + (p[6] + p[7])); \
        union { unsigned u[4]; h8 v; } pa;                                  \
        pa.u[0] = pkrtz(p[0], p[1]);                                        \
        pa.u[1] = pkrtz(p[2], p[3]);                                        \
        pa.u[2] = pkrtz(p[4], p[5]);                                        \
        pa.u[3] = pkrtz(p[6], p[7]);                                        \
        acc[qt][0] = __builtin_amdgcn_mfma_f32_16x16x32_f16(pa.v, VB0, acc[qt][0], 0, 0, 0); \
        acc[qt][1] = __builtin_amdgcn_mfma_f32_16x16x32_f16(pa.v, VB1, acc[qt][1], 0, 0, 0); \
    }                                                                       \
} while (0)

__global__ __launch_bounds__(256, 4) void attn_fp16(
    const unsigned short* __restrict__ qf, const unsigned short* __restrict__ kf,
    const unsigned short* __restrict__ vT, const float* __restrict__ temp,
    unsigned short* __restrict__ pacc,  // [KSPLIT][NQT][32] fp16
    float* __restrict__ pl) {           // [KSPLIT][NQT]
    // XCD-aware swizzle: XCD = bx%8; o contiguous per XCD; sp == XCD id
    const int o  = (blockIdx.x & 7) * 256 + (blockIdx.x >> 3);
    const int qb = o & 15;
    const int bh = (o >> 4) & 15;
    const int sp = o >> 8;
    const int tid  = threadIdx.x;
    const int wv   = tid >> 6;
    const int lane = tid & 63;
    const int col  = lane & 15;
    const int grp  = lane >> 4;

    const int q0 = qb * 256 + wv * 64;
    h8 qa[4];
    #pragma unroll
    for (int qt = 0; qt < 4; ++qt)
        qa[qt] = *reinterpret_cast<const h8*>(
            qf + ((size_t)bh * L + q0 + qt * 16 + col) * D + grp * 8);

    const f4 fz = {0.f, 0.f, 0.f, 0.f};
    f4 acc[4][2] = {{fz, fz}, {fz, fz}, {fz, fz}, {fz, fz}};
    float ls[4] = {};

    const size_t kbase = (size_t)bh * L * D;
    const int kstart = sp * (L / KSPLIT);
    constexpr int SPAN = L / KSPLIT;    // 512

    const bool fast = fabsf(temp[bh & 7]) <= 1.05f;   // poly range guard

    h8 kA0, kA1, vA0, vA1, kB0, kB1, vB0, vB1;
    if (fast) {
        LOADKV(kA0, kA1, vA0, vA1, kstart);
        for (int c = 0; c < SPAN; c += 64) {
            LOADKV(kB0, kB1, vB0, vB1, kstart + c + 32);
            CHUNK(kA0, kA1, vA0, vA1, EXP_POLY);
            const int nx = (c + 64 < SPAN) ? (kstart + c + 64) : kstart;
            LOADKV(kA0, kA1, vA0, vA1, nx);
            CHUNK(kB0, kB1, vB0, vB1, EXP_POLY);
        }
    } else {
        LOADKV(kA0, kA1, vA0, vA1, kstart);
        for (int c = 0; c < SPAN; c += 64) {
            LOADKV(kB0, kB1, vB0, vB1, kstart + c + 32);
            CHUNK(kA0, kA1, vA0, vA1, EXP_HW);
            const int nx = (c + 64 < SPAN) ? (kstart + c + 64) : kstart;
            LOADKV(kA0, kA1, vA0, vA1, nx);
            CHUNK(kB0, kB1, vB0, vB1, EXP_HW);
        }
    }

    // denominators: reduce across the 4 grp groups (lane bits 4,5)
    #pragma unroll
    for (int qt = 0; qt < 4; ++qt) {
        ls[qt] += __shfl_xor(ls[qt], 16);
        ls[qt] += __shfl_xor(ls[qt], 32);
    }

    const size_t pbase = (size_t)sp * NQT + (size_t)bh * L;
    if (lane < 16) {
        #pragma unroll
        for (int qt = 0; qt < 4; ++qt)
            pl[pbase + q0 + qt * 16 + lane] = ls[qt];
    }
    #pragma unroll
    for (int qt = 0; qt < 4; ++qt)
        #pragma unroll
        for (int dt = 0; dt < 2; ++dt)
            #pragma unroll
            for (int r = 0; r < 4; ++r) {
                const int q = q0 + qt * 16 + grp * 4 + r;
                pacc[(pbase + q) * D + dt * 16 + col] = f2h(acc[qt][dt][r]);
            }
}

// ---------------------------------------------------------------------------
// Combine 8 key-splits, normalize, write bf16-split attnout (feeds Wo GEMM).
// ---------------------------------------------------------------------------
__global__ __launch_bounds__(256) void combine_split(
    const unsigned short* __restrict__ pacc, const float* __restrict__ pl,
    unsigned short* __restrict__ ah, unsigned short* __restrict__ al) {
    const int q = blockIdx.x * 256 + threadIdx.x;      // bh*L + l
    float den = 0.f;
    #pragma unroll
    for (int sp = 0; sp < KSPLIT; ++sp) den += pl[(size_t)sp * NQT + q];
    const float inv = 1.0f / den;

    float o[D] = {};
    #pragma unroll
    for (int sp = 0; sp < KSPLIT; ++sp) {
        const unsigned short* a = pacc + ((size_t)sp * NQT + q) * D;
        unsigned short t[D];
        #pragma unroll
        for (int i = 0; i < 4; ++i)
            *reinterpret_cast<uint4*>(&t[i * 8]) = *reinterpret_cast<const uint4*>(a + i * 8);
        #pragma unroll
        for (int d = 0; d < D; ++d) o[d] += h2f(t[d]);
    }

    const int bh = q >> 12, lq = q & 4095;
    const int b = bh >> 3, h = bh & 7;
    unsigned short oh[D], ol[D];
    #pragma unroll
    for (int d = 0; d < D; ++d) {
        float v = o[d] * inv;
        oh[d] = f2bf(v);
        ol[d] = f2bf(v - bf2f(oh[d]));
    }
    const size_t dst = ((size_t)(b * L + lq)) * C + h * D;
    #pragma unroll
    for (int i = 0; i < 4; ++i) {
        *reinterpret_cast<uint4*>(ah + dst + i * 8) = *reinterpret_cast<uint4*>(&oh[i * 8]);
        *reinterpret_cast<uint4*>(al + dst + i * 8) = *reinterpret_cast<uint4*>(&ol[i * 8]);
    }
}

// ---------------------------------------------------------------------------
extern "C" void kernel_launch(void* const* d_in, const int* in_sizes, int n_in,
                              void* d_out, int out_size, void* d_ws, size_t ws_size,
                              hipStream_t stream) {
    const float* x    = (const float*)d_in[0];
    const float* y    = (const float*)d_in[1];
    const float* Wq   = (const float*)d_in[2];
    const float* Wkv  = (const float*)d_in[3];
    const float* Wo   = (const float*)d_in[4];
    const float* temp = (const float*)d_in[5];
    float* out = (float*)d_out;

    // workspace layout (1 MB = 1048576 B), total 47 MB
    char* w = (char*)d_ws;
    constexpr size_t MB = 1048576;
    unsigned short* qf     = (unsigned short*)(w + 0 * MB);      // 4MB
    unsigned short* kf     = (unsigned short*)(w + 4 * MB);      // 4MB
    unsigned short* vT     = (unsigned short*)(w + 8 * MB);      // 4MB
    unsigned short* Wqt_h  = (unsigned short*)(w + 12 * MB);          // 128KB
    unsigned short* Wqt_l  = (unsigned short*)(w + 12 * MB + 131072);
    unsigned short* Wkvt_h = (unsigned short*)(w + 12 * MB + 262144); // 256KB
    unsigned short* Wkvt_l = (unsigned short*)(w + 12 * MB + 524288);
    unsigned short* Wot_h  = (unsigned short*)(w + 12 * MB + 786432); // 128KB
    unsigned short* Wot_l  = (unsigned short*)(w + 12 * MB + 917504);
    float*          pl     = (float*)(w + 13 * MB);              // 2MB [8][NQT]
    unsigned short* xh     = (unsigned short*)(w + 15 * MB);     // 4MB each
    unsigned short* xl     = (unsigned short*)(w + 19 * MB);
    unsigned short* yh     = (unsigned short*)(w + 23 * MB);
    unsigned short* yl     = (unsigned short*)(w + 27 * MB);
    unsigned short* pacc   = xh;     // overlay: [8][NQT][32] fp16 = 32MB (15..47)
    unsigned short* ahg    = qf;     // overlay (qf dead after attn)
    unsigned short* alg    = kf;

    // 1) split x/y + weight transpose/split (one dispatch)
    prep_all<<<3072, 256, 0, stream>>>(x, y, Wq, Wkv, Wo, xh, xl, yh, yl,
                                       Wqt_h, Wqt_l, Wkvt_h, Wkvt_l, Wot_h, Wot_l);

    // 2) merged projections: q/k fused-norm -> qf/kf ; v fused-transpose -> vT
    gemm_proj<<<dim3(M / 64, 12), 256, 0, stream>>>(
        xh, xl, yh, yl, Wqt_h, Wqt_l, Wkvt_h, Wkvt_l, temp, qf, kf, vT);

    // 3) fp16 MFMA attention, KSPLIT=8, XCD swizzle, poly-exp softmax
    attn_fp16<<<2048, 256, 0, stream>>>(qf, kf, vT, temp, pacc, pl);

    // 4) combine splits -> bf16-split attnout (overlays qf/kf)
    combine_split<<<NQT / 256, 256, 0, stream>>>(pacc, pl, ahg, alg);

    // 5) output projection -> d_out
    gemm_mfma<<<dim3(M / 64, C / 64), 256, 0, stream>>>(ahg, alg, Wot_h, Wot_l, out, C);
}

// Round 15
// 180.420 us; speedup vs baseline: 1.0875x; 1.0875x over previous
//
#include <hip/hip_runtime.h>
#include <math.h>

// Problem constants
constexpr int B  = 2;
constexpr int L  = 4096;
constexpr int C  = 256;
constexpr int H  = 8;
constexpr int D  = 32;          // head dim
constexpr int M  = B * L;       // 8192 rows
constexpr int BH = B * H;       // 16
constexpr int KSPLIT = 8;       // one key-split per XCD
constexpr int NQT = BH * L;     // 65536
constexpr float LOG2E = 1.4426950408889634f;

typedef short    s8 __attribute__((ext_vector_type(8)));   // 8 bf16
typedef _Float16 h8 __attribute__((ext_vector_type(8)));   // 8 fp16
typedef __fp16   hp2 __attribute__((ext_vector_type(2)));  // cvt_pkrtz native type
typedef float    f4 __attribute__((ext_vector_type(4)));   // MFMA C/D

__device__ __forceinline__ unsigned short f2bf(float x) {
    unsigned u = __float_as_uint(x);
    u += 0x7fffu + ((u >> 16) & 1u);      // RNE
    return (unsigned short)(u >> 16);
}
__device__ __forceinline__ float bf2f(unsigned short h) {
    return __uint_as_float(((unsigned)h) << 16);
}
__device__ __forceinline__ unsigned pkrtz(float a, float b) {
    union { hp2 h; unsigned u; } c;
    c.h = __builtin_amdgcn_cvt_pkrtz(a, b);   // v_cvt_pkrtz_f16_f32
    return c.u;
}
__device__ __forceinline__ unsigned short f2h(float x) {
    union { _Float16 h; unsigned short u; } c; c.h = (_Float16)x; return c.u;  // RNE
}
__device__ __forceinline__ float h2f(unsigned short u) {
    union { _Float16 h; unsigned short u; } c; c.u = u; return (float)c.h;
}

// ---------------------------------------------------------------------------
// MERGED prep: split x,y into bf16 hi/lo (blocks 0..2047) AND transpose+split
// the 3 weight matrices (blocks 2048..3071). One dispatch.
// ---------------------------------------------------------------------------
__global__ __launch_bounds__(256) void prep_all(
    const float* __restrict__ x, const float* __restrict__ y,
    const float* __restrict__ Wq, const float* __restrict__ Wkv, const float* __restrict__ Wo,
    unsigned short* __restrict__ xh, unsigned short* __restrict__ xl,
    unsigned short* __restrict__ yh, unsigned short* __restrict__ yl,
    unsigned short* __restrict__ Wqt_h, unsigned short* __restrict__ Wqt_l,
    unsigned short* __restrict__ Wkvt_h, unsigned short* __restrict__ Wkvt_l,
    unsigned short* __restrict__ Wot_h, unsigned short* __restrict__ Wot_l) {
    const int bx = blockIdx.x, tid = threadIdx.x;
    if (bx < 2048) {
        const int idx = bx * 256 + tid;                 // 0..524287
        const float* in; unsigned short *oh, *ol; int i;
        if (idx < M * C / 8) { in = x; oh = xh; ol = xl; i = idx; }
        else                 { in = y; oh = yh; ol = yl; i = idx - M * C / 8; }
        float v[8];
        *reinterpret_cast<float4*>(&v[0]) = *reinterpret_cast<const float4*>(in + (size_t)i * 8);
        *reinterpret_cast<float4*>(&v[4]) = *reinterpret_cast<const float4*>(in + (size_t)i * 8 + 4);
        unsigned short hs[8], lo[8];
        #pragma unroll
        for (int j = 0; j < 8; ++j) {
            hs[j] = f2bf(v[j]);
            lo[j] = f2bf(v[j] - bf2f(hs[j]));
        }
        *reinterpret_cast<uint4*>(oh + (size_t)i * 8) = *reinterpret_cast<uint4*>(hs);
        *reinterpret_cast<uint4*>(ol + (size_t)i * 8) = *reinterpret_cast<uint4*>(lo);
    } else {
        const int t = (bx - 2048) * 256 + tid;          // 0..262143
        const float* W; unsigned short *Oh, *Ol; int nlog2, idx;
        if (t < 65536)       { W = Wq;  Oh = Wqt_h;  Ol = Wqt_l;  nlog2 = 8; idx = t; }
        else if (t < 196608) { W = Wkv; Oh = Wkvt_h; Ol = Wkvt_l; nlog2 = 9; idx = t - 65536; }
        else                 { W = Wo;  Oh = Wot_h;  Ol = Wot_l;  nlog2 = 8; idx = t - 196608; }
        const int NN = 1 << nlog2;
        const int n = idx & (NN - 1);
        const int k = idx >> nlog2;
        const float w = W[(size_t)k * NN + n];
        const unsigned short h = f2bf(w);
        Oh[(size_t)n * 256 + k] = h;
        Ol[(size_t)n * 256 + k] = f2bf(w - bf2f(h));
    }
}

// ---------------------------------------------------------------------------
// MERGED projection: q (by 0..3), k (by 4..7), v (by 8..11).
// q/k: fused l2-norm epilogue -> fp16 qf/kf [bh][l][32] (q: temp*LOG2E fold).
// v:   fused transpose+perm epilogue -> fp16 vT[bh][d][slot] directly.
// ---------------------------------------------------------------------------
__global__ __launch_bounds__(256) void gemm_proj(
    const unsigned short* __restrict__ xh, const unsigned short* __restrict__ xl,
    const unsigned short* __restrict__ yh, const unsigned short* __restrict__ yl,
    const unsigned short* __restrict__ Wqt_h, const unsigned short* __restrict__ Wqt_l,
    const unsigned short* __restrict__ Wkvt_h, const unsigned short* __restrict__ Wkvt_l,
    const float* __restrict__ temp,
    unsigned short* __restrict__ qf, unsigned short* __restrict__ kf,
    unsigned short* __restrict__ vT) {
    __shared__ unsigned short lt[64][68];   // v-transpose buffer (8.5KB)
    const int tid  = threadIdx.x;
    const int wv   = tid >> 6;
    const int lane = tid & 63;
    const int col  = lane & 15;
    const int grp  = lane >> 4;
    const int by   = blockIdx.y;
    const bool isq   = (by < 4);
    const bool blk_v = (by >= 8);
    const unsigned short* Ah = isq ? xh : yh;
    const unsigned short* Al = isq ? xl : yl;
    const unsigned short* Wh = isq ? Wqt_h : Wkvt_h;
    const unsigned short* Wl = isq ? Wqt_l : Wkvt_l;
    const int m_blk  = blockIdx.x * 64;
    const int m_base = m_blk + (wv >> 1) * 32;
    const int n_gl   = (isq ? by : by - 4) * 64 + (wv & 1) * 32;  // col in W-space

    const f4 fz = {0.f, 0.f, 0.f, 0.f};
    f4 acc[2][2] = {{fz, fz}, {fz, fz}};

    const size_t a0 = (size_t)(m_base + col) * 256;
    const size_t w0 = (size_t)(n_gl + col) * 256;

    #pragma unroll
    for (int k0 = 0; k0 < 256; k0 += 32) {
        const int ko = k0 + grp * 8;
        s8 ah[2], al[2], wh[2], wl[2];
        #pragma unroll
        for (int mt = 0; mt < 2; ++mt) {
            ah[mt] = *reinterpret_cast<const s8*>(Ah + a0 + (size_t)mt * 16 * 256 + ko);
            al[mt] = *reinterpret_cast<const s8*>(Al + a0 + (size_t)mt * 16 * 256 + ko);
        }
        #pragma unroll
        for (int nt = 0; nt < 2; ++nt) {
            wh[nt] = *reinterpret_cast<const s8*>(Wh + w0 + (size_t)nt * 16 * 256 + ko);
            wl[nt] = *reinterpret_cast<const s8*>(Wl + w0 + (size_t)nt * 16 * 256 + ko);
        }
        #pragma unroll
        for (int mt = 0; mt < 2; ++mt)
            #pragma unroll
            for (int nt = 0; nt < 2; ++nt) {
                acc[mt][nt] = __builtin_amdgcn_mfma_f32_16x16x32_bf16(ah[mt], wh[nt], acc[mt][nt], 0, 0, 0);
                acc[mt][nt] = __builtin_amdgcn_mfma_f32_16x16x32_bf16(al[mt], wh[nt], acc[mt][nt], 0, 0, 0);
                acc[mt][nt] = __builtin_amdgcn_mfma_f32_16x16x32_bf16(ah[mt], wl[nt], acc[mt][nt], 0, 0, 0);
            }
    }

    if (blk_v) {
        // ---- V path: stage 64x64 tile in LDS, then write vT with slot perm
        #pragma unroll
        for (int mt = 0; mt < 2; ++mt)
            #pragma unroll
            for (int nt = 0; nt < 2; ++nt)
                #pragma unroll
                for (int r = 0; r < 4; ++r)
                    lt[(wv >> 1) * 32 + mt * 16 + grp * 4 + r]
                      [(wv & 1) * 32 + nt * 16 + col] = f2h(acc[mt][nt][r]);
        __syncthreads();
        const int dl  = tid & 63;             // d-col within block (0..63)
        const int q4  = tid >> 6;             // 16-key group (0..3)
        const int dgl = (by - 8) * 64 + dl;   // V d-space 0..255
        const int h   = (dgl >> 5) & 7;
        const int dh  = dgl & 31;
        const int b   = m_blk >> 12;
        const int l0  = m_blk & 4095;
        unsigned ow[8];
        #pragma unroll
        for (int i2 = 0; i2 < 8; ++i2) {
            unsigned lohi[2];
            #pragma unroll
            for (int e = 0; e < 2; ++e) {
                const int s  = q4 * 16 + i2 * 2 + e;     // slot within 64 keys
                const int ch = s >> 5;                    // 32-key chunk (0/1)
                const int ws = s & 31;
                const int kl = ch * 32 + ((ws >> 3) << 2) + (((ws & 7) >> 2) << 4) + (ws & 3);
                lohi[e] = lt[kl][dl];
            }
            ow[i2] = lohi[0] | (lohi[1] << 16);
        }
        unsigned short* dst = vT + ((size_t)((b * H + h) * D + dh)) * L + l0 + q4 * 16;
        uint4 u0 = {ow[0], ow[1], ow[2], ow[3]};
        uint4 u1 = {ow[4], ow[5], ow[6], ow[7]};
        *reinterpret_cast<uint4*>(dst)     = u0;
        *reinterpret_cast<uint4*>(dst + 8) = u1;
        return;
    }

    // ---- q/k path: fused l2-norm epilogue
    const int  h  = (n_gl >> 5) & 7;
    const float tl = isq ? temp[h] * LOG2E : 1.0f;   // exp2 fold
    unsigned short* dst = isq ? qf : kf;

    #pragma unroll
    for (int mt = 0; mt < 2; ++mt)
        #pragma unroll
        for (int r = 0; r < 4; ++r) {
            float t = acc[mt][0][r] * acc[mt][0][r] + acc[mt][1][r] * acc[mt][1][r];
            t += __shfl_xor(t, 1);
            t += __shfl_xor(t, 2);
            t += __shfl_xor(t, 4);
            t += __shfl_xor(t, 8);
            const float scale = tl / fmaxf(sqrtf(t), 1e-12f);
            const int row = m_base + mt * 16 + grp * 4 + r;
            const int bb = row >> 12, l = row & 4095;
            const size_t base = ((size_t)(bb * H + h) * L + l) * D;
            dst[base + col]      = f2h(acc[mt][0][r] * scale);
            dst[base + 16 + col] = f2h(acc[mt][1][r] * scale);
        }
}

// ---------------------------------------------------------------------------
// Plain register-only bf16-split MFMA GEMM (output projection), fp32 out.
// ---------------------------------------------------------------------------
__global__ __launch_bounds__(256) void gemm_mfma(
    const unsigned short* __restrict__ Ah, const unsigned short* __restrict__ Al,
    const unsigned short* __restrict__ Wth, const unsigned short* __restrict__ Wtl,
    float* __restrict__ out, int N) {
    const int tid  = threadIdx.x;
    const int wv   = tid >> 6;
    const int lane = tid & 63;
    const int col  = lane & 15;
    const int grp  = lane >> 4;
    const int m_base = blockIdx.x * 64 + (wv >> 1) * 32;
    const int n_base = blockIdx.y * 64 + (wv & 1) * 32;

    const f4 fz = {0.f, 0.f, 0.f, 0.f};
    f4 acc[2][2] = {{fz, fz}, {fz, fz}};

    const size_t a0 = (size_t)(m_base + col) * 256;
    const size_t w0 = (size_t)(n_base + col) * 256;

    #pragma unroll
    for (int k0 = 0; k0 < 256; k0 += 32) {
        const int ko = k0 + grp * 8;
        s8 ah[2], al[2], wh[2], wl[2];
        #pragma unroll
        for (int mt = 0; mt < 2; ++mt) {
            ah[mt] = *reinterpret_cast<const s8*>(Ah + a0 + (size_t)mt * 16 * 256 + ko);
            al[mt] = *reinterpret_cast<const s8*>(Al + a0 + (size_t)mt * 16 * 256 + ko);
        }
        #pragma unroll
        for (int nt = 0; nt < 2; ++nt) {
            wh[nt] = *reinterpret_cast<const s8*>(Wth + w0 + (size_t)nt * 16 * 256 + ko);
            wl[nt] = *reinterpret_cast<const s8*>(Wtl + w0 + (size_t)nt * 16 * 256 + ko);
        }
        #pragma unroll
        for (int mt = 0; mt < 2; ++mt)
            #pragma unroll
            for (int nt = 0; nt < 2; ++nt) {
                acc[mt][nt] = __builtin_amdgcn_mfma_f32_16x16x32_bf16(ah[mt], wh[nt], acc[mt][nt], 0, 0, 0);
                acc[mt][nt] = __builtin_amdgcn_mfma_f32_16x16x32_bf16(al[mt], wh[nt], acc[mt][nt], 0, 0, 0);
                acc[mt][nt] = __builtin_amdgcn_mfma_f32_16x16x32_bf16(ah[mt], wl[nt], acc[mt][nt], 0, 0, 0);
            }
    }

    #pragma unroll
    for (int mt = 0; mt < 2; ++mt)
        #pragma unroll
        for (int nt = 0; nt < 2; ++nt)
            #pragma unroll
            for (int r = 0; r < 4; ++r)
                out[(size_t)(m_base + mt * 16 + grp * 4 + r) * N + n_base + nt * 16 + col] =
                    acc[mt][nt][r];
}

// ---------------------------------------------------------------------------
// fp16 MFMA flash attention (r12 numerics: hw exp2, f32 adds + shfl denom).
// CHANGE vs r12: 2 q-tiles/wave (32 q rows), 4096 blocks (16 blocks/CU
// nominal) for finer packing + more TLP. XCD swizzle: each XCD owns one
// key-split (per-XCD K/V slice 1MB, L2-resident).
// ---------------------------------------------------------------------------
#define LOADKV(KB0, KB1, VB0, VB1, KIDX) do {                               \
    const size_t ko_ = kbase + (size_t)((KIDX) + col) * D + grp * 8;        \
    KB0 = *reinterpret_cast<const h8*>(kf + ko_);                           \
    KB1 = *reinterpret_cast<const h8*>(kf + ko_ + 16 * D);                  \
    const size_t vo_ = kbase + (size_t)col * L + (KIDX) + grp * 8;          \
    VB0 = *reinterpret_cast<const h8*>(vT + vo_);                           \
    VB1 = *reinterpret_cast<const h8*>(vT + vo_ + 16 * L);                  \
} while (0)

#define CHUNK(KB0, KB1, VB0, VB1) do {                                      \
    _Pragma("unroll")                                                       \
    for (int qt = 0; qt < 2; ++qt) {                                        \
        f4 s0 = __builtin_amdgcn_mfma_f32_16x16x32_f16(KB0, qa[qt], fz, 0, 0, 0); \
        f4 s1 = __builtin_amdgcn_mfma_f32_16x16x32_f16(KB1, qa[qt], fz, 0, 0, 0); \
        float p[8];                                                         \
        _Pragma("unroll")                                                   \
        for (int r = 0; r < 4; ++r) {                                       \
            p[r]     = __builtin_amdgcn_exp2f(s0[r]);                       \
            p[r + 4] = __builtin_amdgcn_exp2f(s1[r]);                       \
        }                                                                   \
        ls[qt] += ((p[0] + p[1]) + (p[2] + p[3])) + ((p[4] + p[5]) + (p[6] + p[7])); \
        union { unsigned u[4]; h8 v; } pa;                                  \
        pa.u[0] = pkrtz(p[0], p[1]);                                        \
        pa.u[1] = pkrtz(p[2], p[3]);                                        \
        pa.u[2] = pkrtz(p[4], p[5]);                                        \
        pa.u[3] = pkrtz(p[6], p[7]);                                        \
        acc[qt][0] = __builtin_amdgcn_mfma_f32_16x16x32_f16(pa.v, VB0, acc[qt][0], 0, 0, 0); \
        acc[qt][1] = __builtin_amdgcn_mfma_f32_16x16x32_f16(pa.v, VB1, acc[qt][1], 0, 0, 0); \
    }                                                                       \
} while (0)

__global__ __launch_bounds__(256, 4) void attn_fp16(
    const unsigned short* __restrict__ qf, const unsigned short* __restrict__ kf,
    const unsigned short* __restrict__ vT,
    unsigned short* __restrict__ pacc,  // [KSPLIT][NQT][32] fp16
    float* __restrict__ pl) {           // [KSPLIT][NQT]
    // XCD-aware swizzle: XCD = bx%8; o contiguous per XCD; sp == XCD id
    const int o  = (blockIdx.x & 7) * 512 + (blockIdx.x >> 3);   // bx 0..4095
    const int qb = o & 31;            // 32 q-blocks of 128 rows
    const int bh = (o >> 5) & 15;
    const int sp = o >> 9;            // == bx & 7
    const int tid  = threadIdx.x;
    const int wv   = tid >> 6;
    const int lane = tid & 63;
    const int col  = lane & 15;
    const int grp  = lane >> 4;

    const int q0 = qb * 128 + wv * 32;   // 2 q-tiles (32 rows) per wave
    h8 qa[2];
    #pragma unroll
    for (int qt = 0; qt < 2; ++qt)
        qa[qt] = *reinterpret_cast<const h8*>(
            qf + ((size_t)bh * L + q0 + qt * 16 + col) * D + grp * 8);

    const f4 fz = {0.f, 0.f, 0.f, 0.f};
    f4 acc[2][2] = {{fz, fz}, {fz, fz}};
    float ls[2] = {};

    const size_t kbase = (size_t)bh * L * D;
    const int kstart = sp * (L / KSPLIT);
    constexpr int SPAN = L / KSPLIT;    // 512

    h8 kA0, kA1, vA0, vA1, kB0, kB1, vB0, vB1;
    LOADKV(kA0, kA1, vA0, vA1, kstart);
    for (int c = 0; c < SPAN; c += 64) {
        LOADKV(kB0, kB1, vB0, vB1, kstart + c + 32);
        CHUNK(kA0, kA1, vA0, vA1);
        const int nx = (c + 64 < SPAN) ? (kstart + c + 64) : kstart;  // tail: dummy reload
        LOADKV(kA0, kA1, vA0, vA1, nx);
        CHUNK(kB0, kB1, vB0, vB1);
    }

    // denominators: reduce across the 4 grp groups (lane bits 4,5)
    #pragma unroll
    for (int qt = 0; qt < 2; ++qt) {
        ls[qt] += __shfl_xor(ls[qt], 16);
        ls[qt] += __shfl_xor(ls[qt], 32);
    }

    const size_t pbase = (size_t)sp * NQT + (size_t)bh * L;
    if (lane < 16) {
        #pragma unroll
        for (int qt = 0; qt < 2; ++qt)
            pl[pbase + q0 + qt * 16 + lane] = ls[qt];
    }
    #pragma unroll
    for (int qt = 0; qt < 2; ++qt)
        #pragma unroll
        for (int dt = 0; dt < 2; ++dt)
            #pragma unroll
            for (int r = 0; r < 4; ++r) {
                const int q = q0 + qt * 16 + grp * 4 + r;
                pacc[(pbase + q) * D + dt * 16 + col] = f2h(acc[qt][dt][r]);
            }
}

// ---------------------------------------------------------------------------
// Combine 8 key-splits, normalize, write bf16-split attnout (feeds Wo GEMM).
// ---------------------------------------------------------------------------
__global__ __launch_bounds__(256) void combine_split(
    const unsigned short* __restrict__ pacc, const float* __restrict__ pl,
    unsigned short* __restrict__ ah, unsigned short* __restrict__ al) {
    const int q = blockIdx.x * 256 + threadIdx.x;      // bh*L + l
    float den = 0.f;
    #pragma unroll
    for (int sp = 0; sp < KSPLIT; ++sp) den += pl[(size_t)sp * NQT + q];
    const float inv = 1.0f / den;

    float o[D] = {};
    #pragma unroll
    for (int sp = 0; sp < KSPLIT; ++sp) {
        const unsigned short* a = pacc + ((size_t)sp * NQT + q) * D;
        unsigned short t[D];
        #pragma unroll
        for (int i = 0; i < 4; ++i)
            *reinterpret_cast<uint4*>(&t[i * 8]) = *reinterpret_cast<const uint4*>(a + i * 8);
        #pragma unroll
        for (int d = 0; d < D; ++d) o[d] += h2f(t[d]);
    }

    const int bh = q >> 12, lq = q & 4095;
    const int b = bh >> 3, h = bh & 7;
    unsigned short oh[D], ol[D];
    #pragma unroll
    for (int d = 0; d < D; ++d) {
        float v = o[d] * inv;
        oh[d] = f2bf(v);
        ol[d] = f2bf(v - bf2f(oh[d]));
    }
    const size_t dst = ((size_t)(b * L + lq)) * C + h * D;
    #pragma unroll
    for (int i = 0; i < 4; ++i) {
        *reinterpret_cast<uint4*>(ah + dst + i * 8) = *reinterpret_cast<uint4*>(&oh[i * 8]);
        *reinterpret_cast<uint4*>(al + dst + i * 8) = *reinterpret_cast<uint4*>(&ol[i * 8]);
    }
}

// ---------------------------------------------------------------------------
extern "C" void kernel_launch(void* const* d_in, const int* in_sizes, int n_in,
                              void* d_out, int out_size, void* d_ws, size_t ws_size,
                              hipStream_t stream) {
    const float* x    = (const float*)d_in[0];
    const float* y    = (const float*)d_in[1];
    const float* Wq   = (const float*)d_in[2];
    const float* Wkv  = (const float*)d_in[3];
    const float* Wo   = (const float*)d_in[4];
    const float* temp = (const float*)d_in[5];
    float* out = (float*)d_out;

    // workspace layout (1 MB = 1048576 B), total 47 MB
    char* w = (char*)d_ws;
    constexpr size_t MB = 1048576;
    unsigned short* qf     = (unsigned short*)(w + 0 * MB);      // 4MB
    unsigned short* kf     = (unsigned short*)(w + 4 * MB);      // 4MB
    unsigned short* vT     = (unsigned short*)(w + 8 * MB);      // 4MB
    unsigned short* Wqt_h  = (unsigned short*)(w + 12 * MB);          // 128KB
    unsigned short* Wqt_l  = (unsigned short*)(w + 12 * MB + 131072);
    unsigned short* Wkvt_h = (unsigned short*)(w + 12 * MB + 262144); // 256KB
    unsigned short* Wkvt_l = (unsigned short*)(w + 12 * MB + 524288);
    unsigned short* Wot_h  = (unsigned short*)(w + 12 * MB + 786432); // 128KB
    unsigned short* Wot_l  = (unsigned short*)(w + 12 * MB + 917504);
    float*          pl     = (float*)(w + 13 * MB);              // 2MB [8][NQT]
    unsigned short* xh     = (unsigned short*)(w + 15 * MB);     // 4MB each
    unsigned short* xl     = (unsigned short*)(w + 19 * MB);
    unsigned short* yh     = (unsigned short*)(w + 23 * MB);
    unsigned short* yl     = (unsigned short*)(w + 27 * MB);
    unsigned short* pacc   = xh;     // overlay: [8][NQT][32] fp16 = 32MB (15..47)
    unsigned short* ahg    = qf;     // overlay (qf dead after attn)
    unsigned short* alg    = kf;

    // 1) split x/y + weight transpose/split (one dispatch)
    prep_all<<<3072, 256, 0, stream>>>(x, y, Wq, Wkv, Wo, xh, xl, yh, yl,
                                       Wqt_h, Wqt_l, Wkvt_h, Wkvt_l, Wot_h, Wot_l);

    // 2) merged projections: q/k fused-norm -> qf/kf ; v fused-transpose -> vT
    gemm_proj<<<dim3(M / 64, 12), 256, 0, stream>>>(
        xh, xl, yh, yl, Wqt_h, Wqt_l, Wkvt_h, Wkvt_l, temp, qf, kf, vT);

    // 3) fp16 MFMA attention, KSPLIT=8, XCD swizzle, 4096 fine-grain blocks
    attn_fp16<<<4096, 256, 0, stream>>>(qf, kf, vT, pacc, pl);

    // 4) combine splits -> bf16-split attnout (overlays qf/kf)
    combine_split<<<NQT / 256, 256, 0, stream>>>(pacc, pl, ahg, alg);

    // 5) output projection -> d_out
    gemm_mfma<<<dim3(M / 64, C / 64), 256, 0, stream>>>(ahg, alg, Wot_h, Wot_l, out, C);
}

// Round 16
// 133.149 us; speedup vs baseline: 1.4736x; 1.3550x over previous
//
#include <hip/hip_runtime.h>
#include <math.h>

// Problem constants
constexpr int B  = 2;
constexpr int L  = 4096;
constexpr int C  = 256;
constexpr int H  = 8;
constexpr int D  = 32;          // head dim
constexpr int M  = B * L;       // 8192 rows
constexpr int BH = B * H;       // 16
constexpr int KSPLIT = 8;       // one key-split per XCD
constexpr int NQT = BH * L;     // 65536
constexpr float LOG2E = 1.4426950408889634f;

typedef short    s8 __attribute__((ext_vector_type(8)));   // 8 bf16
typedef _Float16 h8 __attribute__((ext_vector_type(8)));   // 8 fp16
typedef __fp16   hp2 __attribute__((ext_vector_type(2)));  // cvt_pkrtz native type
typedef float    f4 __attribute__((ext_vector_type(4)));   // MFMA C/D

__device__ __forceinline__ unsigned short f2bf(float x) {
    unsigned u = __float_as_uint(x);
    u += 0x7fffu + ((u >> 16) & 1u);      // RNE
    return (unsigned short)(u >> 16);
}
__device__ __forceinline__ float bf2f(unsigned short h) {
    return __uint_as_float(((unsigned)h) << 16);
}
__device__ __forceinline__ unsigned pkrtz(float a, float b) {
    union { hp2 h; unsigned u; } c;
    c.h = __builtin_amdgcn_cvt_pkrtz(a, b);   // v_cvt_pkrtz_f16_f32
    return c.u;
}
__device__ __forceinline__ unsigned short f2h(float x) {
    union { _Float16 h; unsigned short u; } c; c.h = (_Float16)x; return c.u;  // RNE
}
__device__ __forceinline__ float h2f(unsigned short u) {
    union { _Float16 h; unsigned short u; } c; c.u = u; return (float)c.h;
}

// ---------------------------------------------------------------------------
// MERGED prep: split x,y into bf16 hi/lo (blocks 0..2047) AND transpose+split
// the 3 weight matrices (blocks 2048..3071). One dispatch.
// ---------------------------------------------------------------------------
__global__ __launch_bounds__(256) void prep_all(
    const float* __restrict__ x, const float* __restrict__ y,
    const float* __restrict__ Wq, const float* __restrict__ Wkv, const float* __restrict__ Wo,
    unsigned short* __restrict__ xh, unsigned short* __restrict__ xl,
    unsigned short* __restrict__ yh, unsigned short* __restrict__ yl,
    unsigned short* __restrict__ Wqt_h, unsigned short* __restrict__ Wqt_l,
    unsigned short* __restrict__ Wkvt_h, unsigned short* __restrict__ Wkvt_l,
    unsigned short* __restrict__ Wot_h, unsigned short* __restrict__ Wot_l) {
    const int bx = blockIdx.x, tid = threadIdx.x;
    if (bx < 2048) {
        const int idx = bx * 256 + tid;                 // 0..524287
        const float* in; unsigned short *oh, *ol; int i;
        if (idx < M * C / 8) { in = x; oh = xh; ol = xl; i = idx; }
        else                 { in = y; oh = yh; ol = yl; i = idx - M * C / 8; }
        float v[8];
        *reinterpret_cast<float4*>(&v[0]) = *reinterpret_cast<const float4*>(in + (size_t)i * 8);
        *reinterpret_cast<float4*>(&v[4]) = *reinterpret_cast<const float4*>(in + (size_t)i * 8 + 4);
        unsigned short hs[8], lo[8];
        #pragma unroll
        for (int j = 0; j < 8; ++j) {
            hs[j] = f2bf(v[j]);
            lo[j] = f2bf(v[j] - bf2f(hs[j]));
        }
        *reinterpret_cast<uint4*>(oh + (size_t)i * 8) = *reinterpret_cast<uint4*>(hs);
        *reinterpret_cast<uint4*>(ol + (size_t)i * 8) = *reinterpret_cast<uint4*>(lo);
    } else {
        const int t = (bx - 2048) * 256 + tid;          // 0..262143
        const float* W; unsigned short *Oh, *Ol; int nlog2, idx;
        if (t < 65536)       { W = Wq;  Oh = Wqt_h;  Ol = Wqt_l;  nlog2 = 8; idx = t; }
        else if (t < 196608) { W = Wkv; Oh = Wkvt_h; Ol = Wkvt_l; nlog2 = 9; idx = t - 65536; }
        else                 { W = Wo;  Oh = Wot_h;  Ol = Wot_l;  nlog2 = 8; idx = t - 196608; }
        const int NN = 1 << nlog2;
        const int n = idx & (NN - 1);
        const int k = idx >> nlog2;
        const float w = W[(size_t)k * NN + n];
        const unsigned short h = f2bf(w);
        Oh[(size_t)n * 256 + k] = h;
        Ol[(size_t)n * 256 + k] = f2bf(w - bf2f(h));
    }
}

// ---------------------------------------------------------------------------
// MERGED projection: q (by 0..3), k (by 4..7), v (by 8..11).
// q/k: fused l2-norm epilogue -> fp16 qf/kf [bh][l][32] (q: temp*LOG2E fold).
// v:   fused transpose+perm epilogue -> fp16 vT[bh][d][slot] directly.
// ---------------------------------------------------------------------------
__global__ __launch_bounds__(256) void gemm_proj(
    const unsigned short* __restrict__ xh, const unsigned short* __restrict__ xl,
    const unsigned short* __restrict__ yh, const unsigned short* __restrict__ yl,
    const unsigned short* __restrict__ Wqt_h, const unsigned short* __restrict__ Wqt_l,
    const unsigned short* __restrict__ Wkvt_h, const unsigned short* __restrict__ Wkvt_l,
    const float* __restrict__ temp,
    unsigned short* __restrict__ qf, unsigned short* __restrict__ kf,
    unsigned short* __restrict__ vT) {
    __shared__ unsigned short lt[64][68];   // v-transpose buffer (8.5KB)
    const int tid  = threadIdx.x;
    const int wv   = tid >> 6;
    const int lane = tid & 63;
    const int col  = lane & 15;
    const int grp  = lane >> 4;
    const int by   = blockIdx.y;
    const bool isq   = (by < 4);
    const bool blk_v = (by >= 8);
    const unsigned short* Ah = isq ? xh : yh;
    const unsigned short* Al = isq ? xl : yl;
    const unsigned short* Wh = isq ? Wqt_h : Wkvt_h;
    const unsigned short* Wl = isq ? Wqt_l : Wkvt_l;
    const int m_blk  = blockIdx.x * 64;
    const int m_base = m_blk + (wv >> 1) * 32;
    const int n_gl   = (isq ? by : by - 4) * 64 + (wv & 1) * 32;  // col in W-space

    const f4 fz = {0.f, 0.f, 0.f, 0.f};
    f4 acc[2][2] = {{fz, fz}, {fz, fz}};

    const size_t a0 = (size_t)(m_base + col) * 256;
    const size_t w0 = (size_t)(n_gl + col) * 256;

    #pragma unroll
    for (int k0 = 0; k0 < 256; k0 += 32) {
        const int ko = k0 + grp * 8;
        s8 ah[2], al[2], wh[2], wl[2];
        #pragma unroll
        for (int mt = 0; mt < 2; ++mt) {
            ah[mt] = *reinterpret_cast<const s8*>(Ah + a0 + (size_t)mt * 16 * 256 + ko);
            al[mt] = *reinterpret_cast<const s8*>(Al + a0 + (size_t)mt * 16 * 256 + ko);
        }
        #pragma unroll
        for (int nt = 0; nt < 2; ++nt) {
            wh[nt] = *reinterpret_cast<const s8*>(Wh + w0 + (size_t)nt * 16 * 256 + ko);
            wl[nt] = *reinterpret_cast<const s8*>(Wl + w0 + (size_t)nt * 16 * 256 + ko);
        }
        #pragma unroll
        for (int mt = 0; mt < 2; ++mt)
            #pragma unroll
            for (int nt = 0; nt < 2; ++nt) {
                acc[mt][nt] = __builtin_amdgcn_mfma_f32_16x16x32_bf16(ah[mt], wh[nt], acc[mt][nt], 0, 0, 0);
                acc[mt][nt] = __builtin_amdgcn_mfma_f32_16x16x32_bf16(al[mt], wh[nt], acc[mt][nt], 0, 0, 0);
                acc[mt][nt] = __builtin_amdgcn_mfma_f32_16x16x32_bf16(ah[mt], wl[nt], acc[mt][nt], 0, 0, 0);
            }
    }

    if (blk_v) {
        // ---- V path: stage 64x64 tile in LDS, then write vT with slot perm
        #pragma unroll
        for (int mt = 0; mt < 2; ++mt)
            #pragma unroll
            for (int nt = 0; nt < 2; ++nt)
                #pragma unroll
                for (int r = 0; r < 4; ++r)
                    lt[(wv >> 1) * 32 + mt * 16 + grp * 4 + r]
                      [(wv & 1) * 32 + nt * 16 + col] = f2h(acc[mt][nt][r]);
        __syncthreads();
        const int dl  = tid & 63;             // d-col within block (0..63)
        const int q4  = tid >> 6;             // 16-key group (0..3)
        const int dgl = (by - 8) * 64 + dl;   // V d-space 0..255
        const int h   = (dgl >> 5) & 7;
        const int dh  = dgl & 31;
        const int b   = m_blk >> 12;
        const int l0  = m_blk & 4095;
        unsigned ow[8];
        #pragma unroll
        for (int i2 = 0; i2 < 8; ++i2) {
            unsigned lohi[2];
            #pragma unroll
            for (int e = 0; e < 2; ++e) {
                const int s  = q4 * 16 + i2 * 2 + e;     // slot within 64 keys
                const int ch = s >> 5;                    // 32-key chunk (0/1)
                const int ws = s & 31;
                const int kl = ch * 32 + ((ws >> 3) << 2) + (((ws & 7) >> 2) << 4) + (ws & 3);
                lohi[e] = lt[kl][dl];
            }
            ow[i2] = lohi[0] | (lohi[1] << 16);
        }
        unsigned short* dst = vT + ((size_t)((b * H + h) * D + dh)) * L + l0 + q4 * 16;
        uint4 u0 = {ow[0], ow[1], ow[2], ow[3]};
        uint4 u1 = {ow[4], ow[5], ow[6], ow[7]};
        *reinterpret_cast<uint4*>(dst)     = u0;
        *reinterpret_cast<uint4*>(dst + 8) = u1;
        return;
    }

    // ---- q/k path: fused l2-norm epilogue
    const int  h  = (n_gl >> 5) & 7;
    const float tl = isq ? temp[h] * LOG2E : 1.0f;   // exp2 fold
    unsigned short* dst = isq ? qf : kf;

    #pragma unroll
    for (int mt = 0; mt < 2; ++mt)
        #pragma unroll
        for (int r = 0; r < 4; ++r) {
            float t = acc[mt][0][r] * acc[mt][0][r] + acc[mt][1][r] * acc[mt][1][r];
            t += __shfl_xor(t, 1);
            t += __shfl_xor(t, 2);
            t += __shfl_xor(t, 4);
            t += __shfl_xor(t, 8);
            const float scale = tl / fmaxf(sqrtf(t), 1e-12f);
            const int row = m_base + mt * 16 + grp * 4 + r;
            const int bb = row >> 12, l = row & 4095;
            const size_t base = ((size_t)(bb * H + h) * L + l) * D;
            dst[base + col]      = f2h(acc[mt][0][r] * scale);
            dst[base + 16 + col] = f2h(acc[mt][1][r] * scale);
        }
}

// ---------------------------------------------------------------------------
// Plain register-only bf16-split MFMA GEMM (output projection), fp32 out.
// ---------------------------------------------------------------------------
__global__ __launch_bounds__(256) void gemm_mfma(
    const unsigned short* __restrict__ Ah, const unsigned short* __restrict__ Al,
    const unsigned short* __restrict__ Wth, const unsigned short* __restrict__ Wtl,
    float* __restrict__ out, int N) {
    const int tid  = threadIdx.x;
    const int wv   = tid >> 6;
    const int lane = tid & 63;
    const int col  = lane & 15;
    const int grp  = lane >> 4;
    const int m_base = blockIdx.x * 64 + (wv >> 1) * 32;
    const int n_base = blockIdx.y * 64 + (wv & 1) * 32;

    const f4 fz = {0.f, 0.f, 0.f, 0.f};
    f4 acc[2][2] = {{fz, fz}, {fz, fz}};

    const size_t a0 = (size_t)(m_base + col) * 256;
    const size_t w0 = (size_t)(n_base + col) * 256;

    #pragma unroll
    for (int k0 = 0; k0 < 256; k0 += 32) {
        const int ko = k0 + grp * 8;
        s8 ah[2], al[2], wh[2], wl[2];
        #pragma unroll
        for (int mt = 0; mt < 2; ++mt) {
            ah[mt] = *reinterpret_cast<const s8*>(Ah + a0 + (size_t)mt * 16 * 256 + ko);
            al[mt] = *reinterpret_cast<const s8*>(Al + a0 + (size_t)mt * 16 * 256 + ko);
        }
        #pragma unroll
        for (int nt = 0; nt < 2; ++nt) {
            wh[nt] = *reinterpret_cast<const s8*>(Wth + w0 + (size_t)nt * 16 * 256 + ko);
            wl[nt] = *reinterpret_cast<const s8*>(Wtl + w0 + (size_t)nt * 16 * 256 + ko);
        }
        #pragma unroll
        for (int mt = 0; mt < 2; ++mt)
            #pragma unroll
            for (int nt = 0; nt < 2; ++nt) {
                acc[mt][nt] = __builtin_amdgcn_mfma_f32_16x16x32_bf16(ah[mt], wh[nt], acc[mt][nt], 0, 0, 0);
                acc[mt][nt] = __builtin_amdgcn_mfma_f32_16x16x32_bf16(al[mt], wh[nt], acc[mt][nt], 0, 0, 0);
                acc[mt][nt] = __builtin_amdgcn_mfma_f32_16x16x32_bf16(ah[mt], wl[nt], acc[mt][nt], 0, 0, 0);
            }
    }

    #pragma unroll
    for (int mt = 0; mt < 2; ++mt)
        #pragma unroll
        for (int nt = 0; nt < 2; ++nt)
            #pragma unroll
            for (int r = 0; r < 4; ++r)
                out[(size_t)(m_base + mt * 16 + grp * 4 + r) * N + n_base + nt * 16 + col] =
                    acc[mt][nt][r];
}

// ---------------------------------------------------------------------------
// fp16 MFMA flash attention (r12 geometry: 4 q-tiles/wave, 2048 blocks,
// KSPLIT=8, XCD swizzle, hw exp2, f32+shfl denominator).
// NEW: per-block LDS staging of each 32-key K/V chunk (4KB), double-buffered.
// The 4 waves share one staged copy: 1 global dwordx4 load per wave per chunk
// (T14 order: issue load -> compute current -> ds_write -> barrier).
// ---------------------------------------------------------------------------
#define CHUNKL(CUR) do {                                                    \
    h8 kk0 = *reinterpret_cast<const h8*>(&sbuf[CUR][col * 32 + grp * 8]);  \
    h8 kk1 = *reinterpret_cast<const h8*>(&sbuf[CUR][(col + 16) * 32 + grp * 8]); \
    h8 vv0 = *reinterpret_cast<const h8*>(&sbuf[CUR][1024 + col * 32 + grp * 8]); \
    h8 vv1 = *reinterpret_cast<const h8*>(&sbuf[CUR][1024 + (col + 16) * 32 + grp * 8]); \
    _Pragma("unroll")                                                       \
    for (int qt = 0; qt < 4; ++qt) {                                        \
        f4 s0 = __builtin_amdgcn_mfma_f32_16x16x32_f16(kk0, qa[qt], fz, 0, 0, 0); \
        f4 s1 = __builtin_amdgcn_mfma_f32_16x16x32_f16(kk1, qa[qt], fz, 0, 0, 0); \
        float p[8];                                                         \
        _Pragma("unroll")                                                   \
        for (int r = 0; r < 4; ++r) {                                       \
            p[r]     = __builtin_amdgcn_exp2f(s0[r]);                       \
            p[r + 4] = __builtin_amdgcn_exp2f(s1[r]);                       \
        }                                                                   \
        ls[qt] += ((p[0] + p[1]) + (p[2] + p[3])) + ((p[4] + p[5]) + (p[6] + p[7])); \
        union { unsigned u[4]; h8 v; } pa;                                  \
        pa.u[0] = pkrtz(p[0], p[1]);                                        \
        pa.u[1] = pkrtz(p[2], p[3]);                                        \
        pa.u[2] = pkrtz(p[4], p[5]);                                        \
        pa.u[3] = pkrtz(p[6], p[7]);                                        \
        acc[qt][0] = __builtin_amdgcn_mfma_f32_16x16x32_f16(pa.v, vv0, acc[qt][0], 0, 0, 0); \
        acc[qt][1] = __builtin_amdgcn_mfma_f32_16x16x32_f16(pa.v, vv1, acc[qt][1], 0, 0, 0); \
    }                                                                       \
} while (0)

__global__ __launch_bounds__(256, 4) void attn_fp16(
    const unsigned short* __restrict__ qf, const unsigned short* __restrict__ kf,
    const unsigned short* __restrict__ vT,
    unsigned short* __restrict__ pacc,  // [KSPLIT][NQT][32] fp16
    float* __restrict__ pl) {           // [KSPLIT][NQT]
    // sbuf chunk layout: [0..1023] K (key-major [32 keys][32 d]),
    //                    [1024..2047] V (d-major [32 d][32 slots])
    __shared__ __align__(16) unsigned short sbuf[2][2048];

    // XCD-aware swizzle: XCD = bx%8; o contiguous per XCD; sp == XCD id
    const int o  = (blockIdx.x & 7) * 256 + (blockIdx.x >> 3);
    const int qb = o & 15;
    const int bh = (o >> 4) & 15;
    const int sp = o >> 8;
    const int tid  = threadIdx.x;
    const int wv   = tid >> 6;
    const int lane = tid & 63;
    const int col  = lane & 15;
    const int grp  = lane >> 4;

    const int q0 = qb * 256 + wv * 64;
    h8 qa[4];
    #pragma unroll
    for (int qt = 0; qt < 4; ++qt)
        qa[qt] = *reinterpret_cast<const h8*>(
            qf + ((size_t)bh * L + q0 + qt * 16 + col) * D + grp * 8);

    const f4 fz = {0.f, 0.f, 0.f, 0.f};
    f4 acc[4][2] = {{fz, fz}, {fz, fz}, {fz, fz}, {fz, fz}};
    float ls[4] = {};

    const int kstart = sp * (L / KSPLIT);
    constexpr int SPAN = L / KSPLIT;    // 512

    // per-thread staging source: wave 0/1 -> K slice, wave 2/3 -> V slice
    const unsigned short* gsb;
    size_t gmul;
    if (wv < 2) {
        // K: contiguous; slice = keys wv*16..+15 of the chunk
        gsb  = kf + (size_t)bh * L * D + (size_t)wv * 512 + (size_t)lane * 8;
        gmul = 32;                       // elements per key index
    } else {
        // V: d-row (wv-2)*16 + lane>>2, 8 elems at slot offset (lane&3)*8
        gsb  = vT + ((size_t)bh * D + (wv - 2) * 16 + (lane >> 2)) * L + (lane & 3) * 8;
        gmul = 1;
    }
    const int lidx = wv * 512 + lane * 8;    // LDS slice dest (elements)

    #define LOADG(KIDX) (*reinterpret_cast<const uint4*>(gsb + (size_t)(KIDX) * gmul))

    uint4 t = LOADG(kstart);
    *reinterpret_cast<uint4*>(&sbuf[0][lidx]) = t;
    __syncthreads();
    for (int c = 0; c < SPAN; c += 64) {
        t = LOADG(kstart + c + 32);
        CHUNKL(0);
        *reinterpret_cast<uint4*>(&sbuf[1][lidx]) = t;
        __syncthreads();
        const int nx = (c + 64 < SPAN) ? (kstart + c + 64) : kstart;  // tail: dummy
        t = LOADG(nx);
        CHUNKL(1);
        *reinterpret_cast<uint4*>(&sbuf[0][lidx]) = t;
        __syncthreads();
    }
    #undef LOADG

    // denominators: reduce across the 4 grp groups (lane bits 4,5)
    #pragma unroll
    for (int qt = 0; qt < 4; ++qt) {
        ls[qt] += __shfl_xor(ls[qt], 16);
        ls[qt] += __shfl_xor(ls[qt], 32);
    }

    const size_t pbase = (size_t)sp * NQT + (size_t)bh * L;
    if (lane < 16) {
        #pragma unroll
        for (int qt = 0; qt < 4; ++qt)
            pl[pbase + q0 + qt * 16 + lane] = ls[qt];
    }
    #pragma unroll
    for (int qt = 0; qt < 4; ++qt)
        #pragma unroll
        for (int dt = 0; dt < 2; ++dt)
            #pragma unroll
            for (int r = 0; r < 4; ++r) {
                const int q = q0 + qt * 16 + grp * 4 + r;
                pacc[(pbase + q) * D + dt * 16 + col] = f2h(acc[qt][dt][r]);
            }
}

// ---------------------------------------------------------------------------
// Combine 8 key-splits, normalize, write bf16-split attnout (feeds Wo GEMM).
// ---------------------------------------------------------------------------
__global__ __launch_bounds__(256) void combine_split(
    const unsigned short* __restrict__ pacc, const float* __restrict__ pl,
    unsigned short* __restrict__ ah, unsigned short* __restrict__ al) {
    const int q = blockIdx.x * 256 + threadIdx.x;      // bh*L + l
    float den = 0.f;
    #pragma unroll
    for (int sp = 0; sp < KSPLIT; ++sp) den += pl[(size_t)sp * NQT + q];
    const float inv = 1.0f / den;

    float o[D] = {};
    #pragma unroll
    for (int sp = 0; sp < KSPLIT; ++sp) {
        const unsigned short* a = pacc + ((size_t)sp * NQT + q) * D;
        unsigned short t[D];
        #pragma unroll
        for (int i = 0; i < 4; ++i)
            *reinterpret_cast<uint4*>(&t[i * 8]) = *reinterpret_cast<const uint4*>(a + i * 8);
        #pragma unroll
        for (int d = 0; d < D; ++d) o[d] += h2f(t[d]);
    }

    const int bh = q >> 12, lq = q & 4095;
    const int b = bh >> 3, h = bh & 7;
    unsigned short oh[D], ol[D];
    #pragma unroll
    for (int d = 0; d < D; ++d) {
        float v = o[d] * inv;
        oh[d] = f2bf(v);
        ol[d] = f2bf(v - bf2f(oh[d]));
    }
    const size_t dst = ((size_t)(b * L + lq)) * C + h * D;
    #pragma unroll
    for (int i = 0; i < 4; ++i) {
        *reinterpret_cast<uint4*>(ah + dst + i * 8) = *reinterpret_cast<uint4*>(&oh[i * 8]);
        *reinterpret_cast<uint4*>(al + dst + i * 8) = *reinterpret_cast<uint4*>(&ol[i * 8]);
    }
}

// ---------------------------------------------------------------------------
extern "C" void kernel_launch(void* const* d_in, const int* in_sizes, int n_in,
                              void* d_out, int out_size, void* d_ws, size_t ws_size,
                              hipStream_t stream) {
    const float* x    = (const float*)d_in[0];
    const float* y    = (const float*)d_in[1];
    const float* Wq   = (const float*)d_in[2];
    const float* Wkv  = (const float*)d_in[3];
    const float* Wo   = (const float*)d_in[4];
    const float* temp = (const float*)d_in[5];
    float* out = (float*)d_out;

    // workspace layout (1 MB = 1048576 B), total 47 MB
    char* w = (char*)d_ws;
    constexpr size_t MB = 1048576;
    unsigned short* qf     = (unsigned short*)(w + 0 * MB);      // 4MB
    unsigned short* kf     = (unsigned short*)(w + 4 * MB);      // 4MB
    unsigned short* vT     = (unsigned short*)(w + 8 * MB);      // 4MB
    unsigned short* Wqt_h  = (unsigned short*)(w + 12 * MB);          // 128KB
    unsigned short* Wqt_l  = (unsigned short*)(w + 12 * MB + 131072);
    unsigned short* Wkvt_h = (unsigned short*)(w + 12 * MB + 262144); // 256KB
    unsigned short* Wkvt_l = (unsigned short*)(w + 12 * MB + 524288);
    unsigned short* Wot_h  = (unsigned short*)(w + 12 * MB + 786432); // 128KB
    unsigned short* Wot_l  = (unsigned short*)(w + 12 * MB + 917504);
    float*          pl     = (float*)(w + 13 * MB);              // 2MB [8][NQT]
    unsigned short* xh     = (unsigned short*)(w + 15 * MB);     // 4MB each
    unsigned short* xl     = (unsigned short*)(w + 19 * MB);
    unsigned short* yh     = (unsigned short*)(w + 23 * MB);
    unsigned short* yl     = (unsigned short*)(w + 27 * MB);
    unsigned short* pacc   = xh;     // overlay: [8][NQT][32] fp16 = 32MB (15..47)
    unsigned short* ahg    = qf;     // overlay (qf dead after attn)
    unsigned short* alg    = kf;

    // 1) split x/y + weight transpose/split (one dispatch)
    prep_all<<<3072, 256, 0, stream>>>(x, y, Wq, Wkv, Wo, xh, xl, yh, yl,
                                       Wqt_h, Wqt_l, Wkvt_h, Wkvt_l, Wot_h, Wot_l);

    // 2) merged projections: q/k fused-norm -> qf/kf ; v fused-transpose -> vT
    gemm_proj<<<dim3(M / 64, 12), 256, 0, stream>>>(
        xh, xl, yh, yl, Wqt_h, Wqt_l, Wkvt_h, Wkvt_l, temp, qf, kf, vT);

    // 3) fp16 MFMA attention, KSPLIT=8, XCD swizzle, LDS-staged K/V chunks
    attn_fp16<<<2048, 256, 0, stream>>>(qf, kf, vT, pacc, pl);

    // 4) combine splits -> bf16-split attnout (overlays qf/kf)
    combine_split<<<NQT / 256, 256, 0, stream>>>(pacc, pl, ahg, alg);

    // 5) output projection -> d_out
    gemm_mfma<<<dim3(M / 64, C / 64), 256, 0, stream>>>(ahg, alg, Wot_h, Wot_l, out, C);
}

// Round 17
// 98.645 us; speedup vs baseline: 1.9890x; 1.3498x over previous
//
#include <hip/hip_runtime.h>
#include <math.h>

// Problem constants
constexpr int B  = 2;
constexpr int L  = 4096;
constexpr int C  = 256;
constexpr int H  = 8;
constexpr int D  = 32;          // head dim
constexpr int M  = B * L;       // 8192 rows
constexpr int BH = B * H;       // 16
constexpr int KSPLIT = 8;       // one key-split per XCD
constexpr int NQT = BH * L;     // 65536
constexpr float LOG2E = 1.4426950408889634f;

typedef short    s8 __attribute__((ext_vector_type(8)));   // 8 bf16
typedef _Float16 h8 __attribute__((ext_vector_type(8)));   // 8 fp16
typedef __fp16   hp2 __attribute__((ext_vector_type(2)));  // cvt_pkrtz native type
typedef float    f4 __attribute__((ext_vector_type(4)));   // MFMA C/D

__device__ __forceinline__ unsigned short f2bf(float x) {
    unsigned u = __float_as_uint(x);
    u += 0x7fffu + ((u >> 16) & 1u);      // RNE
    return (unsigned short)(u >> 16);
}
__device__ __forceinline__ float bf2f(unsigned short h) {
    return __uint_as_float(((unsigned)h) << 16);
}
__device__ __forceinline__ unsigned pkrtz(float a, float b) {
    union { hp2 h; unsigned u; } c;
    c.h = __builtin_amdgcn_cvt_pkrtz(a, b);   // v_cvt_pkrtz_f16_f32
    return c.u;
}
__device__ __forceinline__ unsigned short f2h(float x) {
    union { _Float16 h; unsigned short u; } c; c.h = (_Float16)x; return c.u;  // RNE
}
__device__ __forceinline__ float h2f(unsigned short u) {
    union { _Float16 h; unsigned short u; } c; c.u = u; return (float)c.h;
}

// ---------------------------------------------------------------------------
// MERGED prep: split x,y into bf16 hi/lo (blocks 0..2047) AND transpose+split
// the 3 weight matrices (blocks 2048..3071). One dispatch.
// ---------------------------------------------------------------------------
__global__ __launch_bounds__(256) void prep_all(
    const float* __restrict__ x, const float* __restrict__ y,
    const float* __restrict__ Wq, const float* __restrict__ Wkv, const float* __restrict__ Wo,
    unsigned short* __restrict__ xh, unsigned short* __restrict__ xl,
    unsigned short* __restrict__ yh, unsigned short* __restrict__ yl,
    unsigned short* __restrict__ Wqt_h, unsigned short* __restrict__ Wqt_l,
    unsigned short* __restrict__ Wkvt_h, unsigned short* __restrict__ Wkvt_l,
    unsigned short* __restrict__ Wot_h, unsigned short* __restrict__ Wot_l) {
    const int bx = blockIdx.x, tid = threadIdx.x;
    if (bx < 2048) {
        const int idx = bx * 256 + tid;                 // 0..524287
        const float* in; unsigned short *oh, *ol; int i;
        if (idx < M * C / 8) { in = x; oh = xh; ol = xl; i = idx; }
        else                 { in = y; oh = yh; ol = yl; i = idx - M * C / 8; }
        float v[8];
        *reinterpret_cast<float4*>(&v[0]) = *reinterpret_cast<const float4*>(in + (size_t)i * 8);
        *reinterpret_cast<float4*>(&v[4]) = *reinterpret_cast<const float4*>(in + (size_t)i * 8 + 4);
        unsigned short hs[8], lo[8];
        #pragma unroll
        for (int j = 0; j < 8; ++j) {
            hs[j] = f2bf(v[j]);
            lo[j] = f2bf(v[j] - bf2f(hs[j]));
        }
        *reinterpret_cast<uint4*>(oh + (size_t)i * 8) = *reinterpret_cast<uint4*>(hs);
        *reinterpret_cast<uint4*>(ol + (size_t)i * 8) = *reinterpret_cast<uint4*>(lo);
    } else {
        const int t = (bx - 2048) * 256 + tid;          // 0..262143
        const float* W; unsigned short *Oh, *Ol; int nlog2, idx;
        if (t < 65536)       { W = Wq;  Oh = Wqt_h;  Ol = Wqt_l;  nlog2 = 8; idx = t; }
        else if (t < 196608) { W = Wkv; Oh = Wkvt_h; Ol = Wkvt_l; nlog2 = 9; idx = t - 65536; }
        else                 { W = Wo;  Oh = Wot_h;  Ol = Wot_l;  nlog2 = 8; idx = t - 196608; }
        const int NN = 1 << nlog2;
        const int n = idx & (NN - 1);
        const int k = idx >> nlog2;
        const float w = W[(size_t)k * NN + n];
        const unsigned short h = f2bf(w);
        Oh[(size_t)n * 256 + k] = h;
        Ol[(size_t)n * 256 + k] = f2bf(w - bf2f(h));
    }
}

// ---------------------------------------------------------------------------
// Staged-GEMM building blocks (shared by gemm_proj / gemm_mfma):
// BK=32 chunks, double-buffered LDS [64 rows][40 elems] per array (row pad
// +8 keeps ds_read banks spread; 80B rows stay 16B-aligned).
// T14 order per chunk: global->reg loads for c+1, compute c from LDS,
// ds_write c+1, one barrier.
// ---------------------------------------------------------------------------
#define GSTAGE_DECL                                                         \
    __shared__ __align__(16) unsigned short sAh[2][2560], sAl[2][2560],     \
                                            sWh[2][2560], sWl[2][2560];

#define GSTAGE_LOAD(TA_H, TA_L, TW_H, TW_L, CI) do {                        \
    TA_H = *reinterpret_cast<const uint4*>(Ah + a_src + (CI) * 32);         \
    TA_L = *reinterpret_cast<const uint4*>(Al + a_src + (CI) * 32);         \
    TW_H = *reinterpret_cast<const uint4*>(Wh + w_src + (CI) * 32);         \
    TW_L = *reinterpret_cast<const uint4*>(Wl + w_src + (CI) * 32);         \
} while (0)

#define GSTAGE_WRITE(BUF, TA_H, TA_L, TW_H, TW_L) do {                      \
    *reinterpret_cast<uint4*>(&sAh[BUF][sdst]) = TA_H;                      \
    *reinterpret_cast<uint4*>(&sAl[BUF][sdst]) = TA_L;                      \
    *reinterpret_cast<uint4*>(&sWh[BUF][sdst]) = TW_H;                      \
    *reinterpret_cast<uint4*>(&sWl[BUF][sdst]) = TW_L;                      \
} while (0)

#define GCOMPUTE(BUF) do {                                                  \
    s8 ah[2], al[2], wh[2], wl[2];                                          \
    _Pragma("unroll")                                                       \
    for (int mt = 0; mt < 2; ++mt) {                                        \
        const int ai = (ar + mt * 16 + col) * 40 + grp * 8;                 \
        ah[mt] = *reinterpret_cast<const s8*>(&sAh[BUF][ai]);               \
        al[mt] = *reinterpret_cast<const s8*>(&sAl[BUF][ai]);               \
    }                                                                       \
    _Pragma("unroll")                                                       \
    for (int nt = 0; nt < 2; ++nt) {                                        \
        const int wi = (wr + nt * 16 + col) * 40 + grp * 8;                 \
        wh[nt] = *reinterpret_cast<const s8*>(&sWh[BUF][wi]);               \
        wl[nt] = *reinterpret_cast<const s8*>(&sWl[BUF][wi]);               \
    }                                                                       \
    _Pragma("unroll")                                                       \
    for (int mt = 0; mt < 2; ++mt)                                          \
        _Pragma("unroll")                                                   \
        for (int nt = 0; nt < 2; ++nt) {                                    \
            acc[mt][nt] = __builtin_amdgcn_mfma_f32_16x16x32_bf16(ah[mt], wh[nt], acc[mt][nt], 0, 0, 0); \
            acc[mt][nt] = __builtin_amdgcn_mfma_f32_16x16x32_bf16(al[mt], wh[nt], acc[mt][nt], 0, 0, 0); \
            acc[mt][nt] = __builtin_amdgcn_mfma_f32_16x16x32_bf16(ah[mt], wl[nt], acc[mt][nt], 0, 0, 0); \
        }                                                                   \
} while (0)

#define GMAIN_LOOP do {                                                     \
    uint4 tAh, tAl, tWh, tWl;                                               \
    GSTAGE_LOAD(tAh, tAl, tWh, tWl, 0);                                     \
    GSTAGE_WRITE(0, tAh, tAl, tWh, tWl);                                    \
    __syncthreads();                                                        \
    for (int c = 0; c < 8; c += 2) {                                        \
        if (c + 1 < 8) GSTAGE_LOAD(tAh, tAl, tWh, tWl, c + 1);              \
        GCOMPUTE(0);                                                        \
        if (c + 1 < 8) GSTAGE_WRITE(1, tAh, tAl, tWh, tWl);                 \
        __syncthreads();                                                    \
        if (c + 2 < 8) GSTAGE_LOAD(tAh, tAl, tWh, tWl, c + 2);              \
        if (c + 1 < 8) GCOMPUTE(1);                                         \
        if (c + 2 < 8) GSTAGE_WRITE(0, tAh, tAl, tWh, tWl);                 \
        __syncthreads();                                                    \
    }                                                                       \
} while (0)

// ---------------------------------------------------------------------------
// MERGED projection: q (by 0..3), k (by 4..7), v (by 8..11). LDS-staged.
// q/k: fused l2-norm epilogue -> fp16 qf/kf [bh][l][32] (q: temp*LOG2E fold).
// v:   fused transpose+perm epilogue -> fp16 vT[bh][d][slot] directly.
// ---------------------------------------------------------------------------
__global__ __launch_bounds__(256) void gemm_proj(
    const unsigned short* __restrict__ xh, const unsigned short* __restrict__ xl,
    const unsigned short* __restrict__ yh, const unsigned short* __restrict__ yl,
    const unsigned short* __restrict__ Wqt_h, const unsigned short* __restrict__ Wqt_l,
    const unsigned short* __restrict__ Wkvt_h, const unsigned short* __restrict__ Wkvt_l,
    const float* __restrict__ temp,
    unsigned short* __restrict__ qf, unsigned short* __restrict__ kf,
    unsigned short* __restrict__ vT) {
    GSTAGE_DECL
    __shared__ unsigned short lt[64][68];   // v-transpose buffer (8.5KB)
    const int tid  = threadIdx.x;
    const int wv   = tid >> 6;
    const int lane = tid & 63;
    const int col  = lane & 15;
    const int grp  = lane >> 4;
    const int by   = blockIdx.y;
    const bool isq   = (by < 4);
    const bool blk_v = (by >= 8);
    const unsigned short* Ah = isq ? xh : yh;
    const unsigned short* Al = isq ? xl : yl;
    const unsigned short* Wh = isq ? Wqt_h : Wkvt_h;
    const unsigned short* Wl = isq ? Wqt_l : Wkvt_l;
    const int m_blk  = blockIdx.x * 64;
    const int n_blk  = (isq ? by : by - 4) * 64;
    const int m_base = m_blk + (wv >> 1) * 32;
    const int n_gl   = n_blk + (wv & 1) * 32;    // col in W-space
    const int ar = (wv >> 1) * 32;
    const int wr = (wv & 1) * 32;

    // staging: thread t stages 16B/array/chunk
    const int srow = tid >> 2;             // 0..63
    const int skg  = (tid & 3) * 8;        // 0,8,16,24
    const size_t a_src = (size_t)(m_blk + srow) * 256 + skg;
    const size_t w_src = (size_t)(n_blk + srow) * 256 + skg;
    const int sdst = srow * 40 + skg;

    const f4 fz = {0.f, 0.f, 0.f, 0.f};
    f4 acc[2][2] = {{fz, fz}, {fz, fz}};

    GMAIN_LOOP;

    if (blk_v) {
        // ---- V path: stage 64x64 tile in LDS, then write vT with slot perm
        #pragma unroll
        for (int mt = 0; mt < 2; ++mt)
            #pragma unroll
            for (int nt = 0; nt < 2; ++nt)
                #pragma unroll
                for (int r = 0; r < 4; ++r)
                    lt[(wv >> 1) * 32 + mt * 16 + grp * 4 + r]
                      [(wv & 1) * 32 + nt * 16 + col] = f2h(acc[mt][nt][r]);
        __syncthreads();
        const int dl  = tid & 63;             // d-col within block (0..63)
        const int q4  = tid >> 6;             // 16-key group (0..3)
        const int dgl = (by - 8) * 64 + dl;   // V d-space 0..255
        const int h   = (dgl >> 5) & 7;
        const int dh  = dgl & 31;
        const int b   = m_blk >> 12;
        const int l0  = m_blk & 4095;
        unsigned ow[8];
        #pragma unroll
        for (int i2 = 0; i2 < 8; ++i2) {
            unsigned lohi[2];
            #pragma unroll
            for (int e = 0; e < 2; ++e) {
                const int s  = q4 * 16 + i2 * 2 + e;     // slot within 64 keys
                const int ch = s >> 5;                    // 32-key chunk (0/1)
                const int ws = s & 31;
                const int kl = ch * 32 + ((ws >> 3) << 2) + (((ws & 7) >> 2) << 4) + (ws & 3);
                lohi[e] = lt[kl][dl];
            }
            ow[i2] = lohi[0] | (lohi[1] << 16);
        }
        unsigned short* dst = vT + ((size_t)((b * H + h) * D + dh)) * L + l0 + q4 * 16;
        uint4 u0 = {ow[0], ow[1], ow[2], ow[3]};
        uint4 u1 = {ow[4], ow[5], ow[6], ow[7]};
        *reinterpret_cast<uint4*>(dst)     = u0;
        *reinterpret_cast<uint4*>(dst + 8) = u1;
        return;
    }

    // ---- q/k path: fused l2-norm epilogue
    const int  h  = (n_gl >> 5) & 7;
    const float tl = isq ? temp[h] * LOG2E : 1.0f;   // exp2 fold
    unsigned short* dst = isq ? qf : kf;

    #pragma unroll
    for (int mt = 0; mt < 2; ++mt)
        #pragma unroll
        for (int r = 0; r < 4; ++r) {
            float t = acc[mt][0][r] * acc[mt][0][r] + acc[mt][1][r] * acc[mt][1][r];
            t += __shfl_xor(t, 1);
            t += __shfl_xor(t, 2);
            t += __shfl_xor(t, 4);
            t += __shfl_xor(t, 8);
            const float scale = tl / fmaxf(sqrtf(t), 1e-12f);
            const int row = m_base + mt * 16 + grp * 4 + r;
            const int bb = row >> 12, l = row & 4095;
            const size_t base = ((size_t)(bb * H + h) * L + l) * D;
            dst[base + col]      = f2h(acc[mt][0][r] * scale);
            dst[base + 16 + col] = f2h(acc[mt][1][r] * scale);
        }
}

// ---------------------------------------------------------------------------
// Output projection GEMM (LDS-staged, same structure), fp32 out.
// ---------------------------------------------------------------------------
__global__ __launch_bounds__(256) void gemm_mfma(
    const unsigned short* __restrict__ Ahp, const unsigned short* __restrict__ Alp,
    const unsigned short* __restrict__ Wth, const unsigned short* __restrict__ Wtl,
    float* __restrict__ out, int N) {
    GSTAGE_DECL
    const int tid  = threadIdx.x;
    const int wv   = tid >> 6;
    const int lane = tid & 63;
    const int col  = lane & 15;
    const int grp  = lane >> 4;
    const int m_blk  = blockIdx.x * 64;
    const int n_blk  = blockIdx.y * 64;
    const int m_base = m_blk + (wv >> 1) * 32;
    const int n_base = n_blk + (wv & 1) * 32;
    const int ar = (wv >> 1) * 32;
    const int wr = (wv & 1) * 32;

    const unsigned short* Ah = Ahp;
    const unsigned short* Al = Alp;
    const unsigned short* Wh = Wth;
    const unsigned short* Wl = Wtl;

    const int srow = tid >> 2;
    const int skg  = (tid & 3) * 8;
    const size_t a_src = (size_t)(m_blk + srow) * 256 + skg;
    const size_t w_src = (size_t)(n_blk + srow) * 256 + skg;
    const int sdst = srow * 40 + skg;

    const f4 fz = {0.f, 0.f, 0.f, 0.f};
    f4 acc[2][2] = {{fz, fz}, {fz, fz}};

    GMAIN_LOOP;

    #pragma unroll
    for (int mt = 0; mt < 2; ++mt)
        #pragma unroll
        for (int nt = 0; nt < 2; ++nt)
            #pragma unroll
            for (int r = 0; r < 4; ++r)
                out[(size_t)(m_base + mt * 16 + grp * 4 + r) * N + n_base + nt * 16 + col] =
                    acc[mt][nt][r];
}

// ---------------------------------------------------------------------------
// fp16 MFMA flash attention (r16: 4 q-tiles/wave, 2048 blocks, KSPLIT=8,
// XCD swizzle, hw exp2, LDS-staged double-buffered K/V chunks).
// ---------------------------------------------------------------------------
#define CHUNKL(CUR) do {                                                    \
    h8 kk0 = *reinterpret_cast<const h8*>(&sbuf[CUR][col * 32 + grp * 8]);  \
    h8 kk1 = *reinterpret_cast<const h8*>(&sbuf[CUR][(col + 16) * 32 + grp * 8]); \
    h8 vv0 = *reinterpret_cast<const h8*>(&sbuf[CUR][1024 + col * 32 + grp * 8]); \
    h8 vv1 = *reinterpret_cast<const h8*>(&sbuf[CUR][1024 + (col + 16) * 32 + grp * 8]); \
    _Pragma("unroll")                                                       \
    for (int qt = 0; qt < 4; ++qt) {                                        \
        f4 s0 = __builtin_amdgcn_mfma_f32_16x16x32_f16(kk0, qa[qt], fz, 0, 0, 0); \
        f4 s1 = __builtin_amdgcn_mfma_f32_16x16x32_f16(kk1, qa[qt], fz, 0, 0, 0); \
        float p[8];                                                         \
        _Pragma("unroll")                                                   \
        for (int r = 0; r < 4; ++r) {                                       \
            p[r]     = __builtin_amdgcn_exp2f(s0[r]);                       \
            p[r + 4] = __builtin_amdgcn_exp2f(s1[r]);                       \
        }                                                                   \
        ls[qt] += ((p[0] + p[1]) + (p[2] + p[3])) + ((p[4] + p[5]) + (p[6] + p[7])); \
        union { unsigned u[4]; h8 v; } pa;                                  \
        pa.u[0] = pkrtz(p[0], p[1]);                                        \
        pa.u[1] = pkrtz(p[2], p[3]);                                        \
        pa.u[2] = pkrtz(p[4], p[5]);                                        \
        pa.u[3] = pkrtz(p[6], p[7]);                                        \
        acc[qt][0] = __builtin_amdgcn_mfma_f32_16x16x32_f16(pa.v, vv0, acc[qt][0], 0, 0, 0); \
        acc[qt][1] = __builtin_amdgcn_mfma_f32_16x16x32_f16(pa.v, vv1, acc[qt][1], 0, 0, 0); \
    }                                                                       \
} while (0)

__global__ __launch_bounds__(256, 4) void attn_fp16(
    const unsigned short* __restrict__ qf, const unsigned short* __restrict__ kf,
    const unsigned short* __restrict__ vT,
    unsigned short* __restrict__ pacc,  // [KSPLIT][NQT][32] fp16
    float* __restrict__ pl) {           // [KSPLIT][NQT]
    // sbuf chunk layout: [0..1023] K (key-major [32 keys][32 d]),
    //                    [1024..2047] V (d-major [32 d][32 slots])
    __shared__ __align__(16) unsigned short sbuf[2][2048];

    // XCD-aware swizzle: XCD = bx%8; o contiguous per XCD; sp == XCD id
    const int o  = (blockIdx.x & 7) * 256 + (blockIdx.x >> 3);
    const int qb = o & 15;
    const int bh = (o >> 4) & 15;
    const int sp = o >> 8;
    const int tid  = threadIdx.x;
    const int wv   = tid >> 6;
    const int lane = tid & 63;
    const int col  = lane & 15;
    const int grp  = lane >> 4;

    const int q0 = qb * 256 + wv * 64;
    h8 qa[4];
    #pragma unroll
    for (int qt = 0; qt < 4; ++qt)
        qa[qt] = *reinterpret_cast<const h8*>(
            qf + ((size_t)bh * L + q0 + qt * 16 + col) * D + grp * 8);

    const f4 fz = {0.f, 0.f, 0.f, 0.f};
    f4 acc[4][2] = {{fz, fz}, {fz, fz}, {fz, fz}, {fz, fz}};
    float ls[4] = {};

    const int kstart = sp * (L / KSPLIT);
    constexpr int SPAN = L / KSPLIT;    // 512

    // per-thread staging source: wave 0/1 -> K slice, wave 2/3 -> V slice
    const unsigned short* gsb;
    size_t gmul;
    if (wv < 2) {
        gsb  = kf + (size_t)bh * L * D + (size_t)wv * 512 + (size_t)lane * 8;
        gmul = 32;
    } else {
        gsb  = vT + ((size_t)bh * D + (wv - 2) * 16 + (lane >> 2)) * L + (lane & 3) * 8;
        gmul = 1;
    }
    const int lidx = wv * 512 + lane * 8;

    #define LOADG(KIDX) (*reinterpret_cast<const uint4*>(gsb + (size_t)(KIDX) * gmul))

    uint4 t = LOADG(kstart);
    *reinterpret_cast<uint4*>(&sbuf[0][lidx]) = t;
    __syncthreads();
    for (int c = 0; c < SPAN; c += 64) {
        t = LOADG(kstart + c + 32);
        CHUNKL(0);
        *reinterpret_cast<uint4*>(&sbuf[1][lidx]) = t;
        __syncthreads();
        const int nx = (c + 64 < SPAN) ? (kstart + c + 64) : kstart;  // tail: dummy
        t = LOADG(nx);
        CHUNKL(1);
        *reinterpret_cast<uint4*>(&sbuf[0][lidx]) = t;
        __syncthreads();
    }
    #undef LOADG

    // denominators: reduce across the 4 grp groups (lane bits 4,5)
    #pragma unroll
    for (int qt = 0; qt < 4; ++qt) {
        ls[qt] += __shfl_xor(ls[qt], 16);
        ls[qt] += __shfl_xor(ls[qt], 32);
    }

    const size_t pbase = (size_t)sp * NQT + (size_t)bh * L;
    if (lane < 16) {
        #pragma unroll
        for (int qt = 0; qt < 4; ++qt)
            pl[pbase + q0 + qt * 16 + lane] = ls[qt];
    }
    #pragma unroll
    for (int qt = 0; qt < 4; ++qt)
        #pragma unroll
        for (int dt = 0; dt < 2; ++dt)
            #pragma unroll
            for (int r = 0; r < 4; ++r) {
                const int q = q0 + qt * 16 + grp * 4 + r;
                pacc[(pbase + q) * D + dt * 16 + col] = f2h(acc[qt][dt][r]);
            }
}

// ---------------------------------------------------------------------------
// Combine 8 key-splits, normalize, write bf16-split attnout (feeds Wo GEMM).
// ---------------------------------------------------------------------------
__global__ __launch_bounds__(256) void combine_split(
    const unsigned short* __restrict__ pacc, const float* __restrict__ pl,
    unsigned short* __restrict__ ah, unsigned short* __restrict__ al) {
    const int q = blockIdx.x * 256 + threadIdx.x;      // bh*L + l
    float den = 0.f;
    #pragma unroll
    for (int sp = 0; sp < KSPLIT; ++sp) den += pl[(size_t)sp * NQT + q];
    const float inv = 1.0f / den;

    float o[D] = {};
    #pragma unroll
    for (int sp = 0; sp < KSPLIT; ++sp) {
        const unsigned short* a = pacc + ((size_t)sp * NQT + q) * D;
        unsigned short t[D];
        #pragma unroll
        for (int i = 0; i < 4; ++i)
            *reinterpret_cast<uint4*>(&t[i * 8]) = *reinterpret_cast<const uint4*>(a + i * 8);
        #pragma unroll
        for (int d = 0; d < D; ++d) o[d] += h2f(t[d]);
    }

    const int bh = q >> 12, lq = q & 4095;
    const int b = bh >> 3, h = bh & 7;
    unsigned short oh[D], ol[D];
    #pragma unroll
    for (int d = 0; d < D; ++d) {
        float v = o[d] * inv;
        oh[d] = f2bf(v);
        ol[d] = f2bf(v - bf2f(oh[d]));
    }
    const size_t dst = ((size_t)(b * L + lq)) * C + h * D;
    #pragma unroll
    for (int i = 0; i < 4; ++i) {
        *reinterpret_cast<uint4*>(ah + dst + i * 8) = *reinterpret_cast<uint4*>(&oh[i * 8]);
        *reinterpret_cast<uint4*>(al + dst + i * 8) = *reinterpret_cast<uint4*>(&ol[i * 8]);
    }
}

// ---------------------------------------------------------------------------
extern "C" void kernel_launch(void* const* d_in, const int* in_sizes, int n_in,
                              void* d_out, int out_size, void* d_ws, size_t ws_size,
                              hipStream_t stream) {
    const float* x    = (const float*)d_in[0];
    const float* y    = (const float*)d_in[1];
    const float* Wq   = (const float*)d_in[2];
    const float* Wkv  = (const float*)d_in[3];
    const float* Wo   = (const float*)d_in[4];
    const float* temp = (const float*)d_in[5];
    float* out = (float*)d_out;

    // workspace layout (1 MB = 1048576 B), total 47 MB
    char* w = (char*)d_ws;
    constexpr size_t MB = 1048576;
    unsigned short* qf     = (unsigned short*)(w + 0 * MB);      // 4MB
    unsigned short* kf     = (unsigned short*)(w + 4 * MB);      // 4MB
    unsigned short* vT     = (unsigned short*)(w + 8 * MB);      // 4MB
    unsigned short* Wqt_h  = (unsigned short*)(w + 12 * MB);          // 128KB
    unsigned short* Wqt_l  = (unsigned short*)(w + 12 * MB + 131072);
    unsigned short* Wkvt_h = (unsigned short*)(w + 12 * MB + 262144); // 256KB
    unsigned short* Wkvt_l = (unsigned short*)(w + 12 * MB + 524288);
    unsigned short* Wot_h  = (unsigned short*)(w + 12 * MB + 786432); // 128KB
    unsigned short* Wot_l  = (unsigned short*)(w + 12 * MB + 917504);
    float*          pl     = (float*)(w + 13 * MB);              // 2MB [8][NQT]
    unsigned short* xh     = (unsigned short*)(w + 15 * MB);     // 4MB each
    unsigned short* xl     = (unsigned short*)(w + 19 * MB);
    unsigned short* yh     = (unsigned short*)(w + 23 * MB);
    unsigned short* yl     = (unsigned short*)(w + 27 * MB);
    unsigned short* pacc   = xh;     // overlay: [8][NQT][32] fp16 = 32MB (15..47)
    unsigned short* ahg    = qf;     // overlay (qf dead after attn)
    unsigned short* alg    = kf;

    // 1) split x/y + weight transpose/split (one dispatch)
    prep_all<<<3072, 256, 0, stream>>>(x, y, Wq, Wkv, Wo, xh, xl, yh, yl,
                                       Wqt_h, Wqt_l, Wkvt_h, Wkvt_l, Wot_h, Wot_l);

    // 2) merged projections (LDS-staged): q/k fused-norm -> qf/kf ; v -> vT
    gemm_proj<<<dim3(M / 64, 12), 256, 0, stream>>>(
        xh, xl, yh, yl, Wqt_h, Wqt_l, Wkvt_h, Wkvt_l, temp, qf, kf, vT);

    // 3) fp16 MFMA attention, KSPLIT=8, XCD swizzle, LDS-staged K/V chunks
    attn_fp16<<<2048, 256, 0, stream>>>(qf, kf, vT, pacc, pl);

    // 4) combine splits -> bf16-split attnout (overlays qf/kf)
    combine_split<<<NQT / 256, 256, 0, stream>>>(pacc, pl, ahg, alg);

    // 5) output projection (LDS-staged) -> d_out
    gemm_mfma<<<dim3(M / 64, C / 64), 256, 0, stream>>>(ahg, alg, Wot_h, Wot_l, out, C);
}

// Round 18
// 96.422 us; speedup vs baseline: 2.0349x; 1.0231x over previous
//
#include <hip/hip_runtime.h>
#include <math.h>

// Problem constants
constexpr int B  = 2;
constexpr int L  = 4096;
constexpr int C  = 256;
constexpr int H  = 8;
constexpr int D  = 32;          // head dim
constexpr int M  = B * L;       // 8192 rows
constexpr int BH = B * H;       // 16
constexpr int KSPLIT = 8;       // one key-split per XCD
constexpr int NQT = BH * L;     // 65536
constexpr float LOG2E = 1.4426950408889634f;

typedef short    s8 __attribute__((ext_vector_type(8)));   // 8 bf16
typedef _Float16 h8 __attribute__((ext_vector_type(8)));   // 8 fp16
typedef __fp16   hp2 __attribute__((ext_vector_type(2)));  // cvt_pkrtz native type
typedef float    f4 __attribute__((ext_vector_type(4)));   // MFMA C/D

__device__ __forceinline__ unsigned short f2bf(float x) {
    unsigned u = __float_as_uint(x);
    u += 0x7fffu + ((u >> 16) & 1u);      // RNE
    return (unsigned short)(u >> 16);
}
__device__ __forceinline__ float bf2f(unsigned short h) {
    return __uint_as_float(((unsigned)h) << 16);
}
__device__ __forceinline__ unsigned pkrtz(float a, float b) {
    union { hp2 h; unsigned u; } c;
    c.h = __builtin_amdgcn_cvt_pkrtz(a, b);   // v_cvt_pkrtz_f16_f32
    return c.u;
}
__device__ __forceinline__ unsigned short f2h(float x) {
    union { _Float16 h; unsigned short u; } c; c.h = (_Float16)x; return c.u;  // RNE
}
__device__ __forceinline__ float h2f(unsigned short u) {
    union { _Float16 h; unsigned short u; } c; c.u = u; return (float)c.h;
}

// ---------------------------------------------------------------------------
// Weights-only prep: transpose + bf16-split the 3 weight matrices.
// (x/y splitting is fused into gemm_proj's staging.)
// ---------------------------------------------------------------------------
__global__ __launch_bounds__(256) void prep_w(
    const float* __restrict__ Wq, const float* __restrict__ Wkv, const float* __restrict__ Wo,
    unsigned short* __restrict__ Wqt_h, unsigned short* __restrict__ Wqt_l,
    unsigned short* __restrict__ Wkvt_h, unsigned short* __restrict__ Wkvt_l,
    unsigned short* __restrict__ Wot_h, unsigned short* __restrict__ Wot_l) {
    const int t = blockIdx.x * 256 + threadIdx.x;   // 0..262143
    const float* W; unsigned short *Oh, *Ol; int nlog2, idx;
    if (t < 65536)       { W = Wq;  Oh = Wqt_h;  Ol = Wqt_l;  nlog2 = 8; idx = t; }
    else if (t < 196608) { W = Wkv; Oh = Wkvt_h; Ol = Wkvt_l; nlog2 = 9; idx = t - 65536; }
    else                 { W = Wo;  Oh = Wot_h;  Ol = Wot_l;  nlog2 = 8; idx = t - 196608; }
    const int NN = 1 << nlog2;
    const int n = idx & (NN - 1);
    const int k = idx >> nlog2;
    const float w = W[(size_t)k * NN + n];
    const unsigned short h = f2bf(w);
    Oh[(size_t)n * 256 + k] = h;
    Ol[(size_t)n * 256 + k] = f2bf(w - bf2f(h));
}

// ---------------------------------------------------------------------------
// Staged-GEMM building blocks. BK=32 chunks, double-buffered LDS
// [64 rows][40 elems] per array (row pad +8; 80B rows stay 16B-aligned).
// T14 order per chunk: global->reg loads for c+1, compute c, ds_write, barrier.
// ---------------------------------------------------------------------------
#define GSTAGE_DECL                                                         \
    __shared__ __align__(16) unsigned short sAh[2][2560], sAl[2][2560],     \
                                            sWh[2][2560], sWl[2][2560];

#define GCOMPUTE(BUF) do {                                                  \
    s8 ah[2], al[2], wh[2], wl[2];                                          \
    _Pragma("unroll")                                                       \
    for (int mt = 0; mt < 2; ++mt) {                                        \
        const int ai = (ar + mt * 16 + col) * 40 + grp * 8;                 \
        ah[mt] = *reinterpret_cast<const s8*>(&sAh[BUF][ai]);               \
        al[mt] = *reinterpret_cast<const s8*>(&sAl[BUF][ai]);               \
    }                                                                       \
    _Pragma("unroll")                                                       \
    for (int nt = 0; nt < 2; ++nt) {                                        \
        const int wi = (wr + nt * 16 + col) * 40 + grp * 8;                 \
        wh[nt] = *reinterpret_cast<const s8*>(&sWh[BUF][wi]);               \
        wl[nt] = *reinterpret_cast<const s8*>(&sWl[BUF][wi]);               \
    }                                                                       \
    _Pragma("unroll")                                                       \
    for (int mt = 0; mt < 2; ++mt)                                          \
        _Pragma("unroll")                                                   \
        for (int nt = 0; nt < 2; ++nt) {                                    \
            acc[mt][nt] = __builtin_amdgcn_mfma_f32_16x16x32_bf16(ah[mt], wh[nt], acc[mt][nt], 0, 0, 0); \
            acc[mt][nt] = __builtin_amdgcn_mfma_f32_16x16x32_bf16(al[mt], wh[nt], acc[mt][nt], 0, 0, 0); \
            acc[mt][nt] = __builtin_amdgcn_mfma_f32_16x16x32_bf16(ah[mt], wl[nt], acc[mt][nt], 0, 0, 0); \
        }                                                                   \
} while (0)

// --- bf16-A variant (gemm_mfma: Wo projection) ---
#define GSTAGE_LOAD(TA_H, TA_L, TW_H, TW_L, CI) do {                        \
    TA_H = *reinterpret_cast<const uint4*>(Ah + a_src + (CI) * 32);         \
    TA_L = *reinterpret_cast<const uint4*>(Al + a_src + (CI) * 32);         \
    TW_H = *reinterpret_cast<const uint4*>(Wh + w_src + (CI) * 32);         \
    TW_L = *reinterpret_cast<const uint4*>(Wl + w_src + (CI) * 32);         \
} while (0)

#define GSTAGE_WRITE(BUF, TA_H, TA_L, TW_H, TW_L) do {                      \
    *reinterpret_cast<uint4*>(&sAh[BUF][sdst]) = TA_H;                      \
    *reinterpret_cast<uint4*>(&sAl[BUF][sdst]) = TA_L;                      \
    *reinterpret_cast<uint4*>(&sWh[BUF][sdst]) = TW_H;                      \
    *reinterpret_cast<uint4*>(&sWl[BUF][sdst]) = TW_L;                      \
} while (0)

#define GMAIN_LOOP do {                                                     \
    uint4 tAh, tAl, tWh, tWl;                                               \
    GSTAGE_LOAD(tAh, tAl, tWh, tWl, 0);                                     \
    GSTAGE_WRITE(0, tAh, tAl, tWh, tWl);                                    \
    __syncthreads();                                                        \
    for (int c = 0; c < 8; c += 2) {                                        \
        if (c + 1 < 8) GSTAGE_LOAD(tAh, tAl, tWh, tWl, c + 1);              \
        GCOMPUTE(0);                                                        \
        if (c + 1 < 8) GSTAGE_WRITE(1, tAh, tAl, tWh, tWl);                 \
        __syncthreads();                                                    \
        if (c + 2 < 8) GSTAGE_LOAD(tAh, tAl, tWh, tWl, c + 2);              \
        if (c + 1 < 8) GCOMPUTE(1);                                         \
        if (c + 2 < 8) GSTAGE_WRITE(0, tAh, tAl, tWh, tWl);                 \
        __syncthreads();                                                    \
    }                                                                       \
} while (0)

// --- fp32-A variant (gemm_proj: reads raw x/y, splits during staging) ---
#define PSTAGE_LOAD(FA0, FA1, TW_H, TW_L, CI) do {                          \
    FA0 = *reinterpret_cast<const float4*>(Af + a_srcf + (CI) * 32);        \
    FA1 = *reinterpret_cast<const float4*>(Af + a_srcf + (CI) * 32 + 4);    \
    TW_H = *reinterpret_cast<const uint4*>(Wh + w_src + (CI) * 32);         \
    TW_L = *reinterpret_cast<const uint4*>(Wl + w_src + (CI) * 32);         \
} while (0)

#define PSTAGE_WRITE(BUF, FA0, FA1, TW_H, TW_L) do {                        \
    float vv[8];                                                            \
    *reinterpret_cast<float4*>(&vv[0]) = FA0;                               \
    *reinterpret_cast<float4*>(&vv[4]) = FA1;                               \
    unsigned short hs_[8], lo_[8];                                          \
    _Pragma("unroll")                                                       \
    for (int j = 0; j < 8; ++j) {                                           \
        hs_[j] = f2bf(vv[j]);                                               \
        lo_[j] = f2bf(vv[j] - bf2f(hs_[j]));                                \
    }                                                                       \
    *reinterpret_cast<uint4*>(&sAh[BUF][sdst]) = *reinterpret_cast<uint4*>(hs_); \
    *reinterpret_cast<uint4*>(&sAl[BUF][sdst]) = *reinterpret_cast<uint4*>(lo_); \
    *reinterpret_cast<uint4*>(&sWh[BUF][sdst]) = TW_H;                      \
    *reinterpret_cast<uint4*>(&sWl[BUF][sdst]) = TW_L;                      \
} while (0)

#define PMAIN_LOOP do {                                                     \
    float4 fa0, fa1; uint4 tWh, tWl;                                        \
    PSTAGE_LOAD(fa0, fa1, tWh, tWl, 0);                                     \
    PSTAGE_WRITE(0, fa0, fa1, tWh, tWl);                                    \
    __syncthreads();                                                        \
    for (int c = 0; c < 8; c += 2) {                                        \
        if (c + 1 < 8) PSTAGE_LOAD(fa0, fa1, tWh, tWl, c + 1);              \
        GCOMPUTE(0);                                                        \
        if (c + 1 < 8) PSTAGE_WRITE(1, fa0, fa1, tWh, tWl);                 \
        __syncthreads();                                                    \
        if (c + 2 < 8) PSTAGE_LOAD(fa0, fa1, tWh, tWl, c + 2);              \
        if (c + 1 < 8) GCOMPUTE(1);                                         \
        if (c + 2 < 8) PSTAGE_WRITE(0, fa0, fa1, tWh, tWl);                 \
        __syncthreads();                                                    \
    }                                                                       \
} while (0)

// ---------------------------------------------------------------------------
// MERGED projection: q (by 0..3), k (by 4..7), v (by 8..11). LDS-staged with
// FUSED fp32->bf16 hi/lo split of x/y during staging (no xh..yl buffers).
// q/k: fused l2-norm epilogue -> fp16 qf/kf [bh][l][32] (q: temp*LOG2E fold).
// v:   fused transpose+perm epilogue -> fp16 vT[bh][d][slot] directly.
// ---------------------------------------------------------------------------
__global__ __launch_bounds__(256) void gemm_proj(
    const float* __restrict__ x, const float* __restrict__ y,
    const unsigned short* __restrict__ Wqt_h, const unsigned short* __restrict__ Wqt_l,
    const unsigned short* __restrict__ Wkvt_h, const unsigned short* __restrict__ Wkvt_l,
    const float* __restrict__ temp,
    unsigned short* __restrict__ qf, unsigned short* __restrict__ kf,
    unsigned short* __restrict__ vT) {
    GSTAGE_DECL
    __shared__ unsigned short lt[64][68];   // v-transpose buffer (8.5KB)
    const int tid  = threadIdx.x;
    const int wv   = tid >> 6;
    const int lane = tid & 63;
    const int col  = lane & 15;
    const int grp  = lane >> 4;
    const int by   = blockIdx.y;
    const bool isq   = (by < 4);
    const bool blk_v = (by >= 8);
    const float* Af = isq ? x : y;
    const unsigned short* Wh = isq ? Wqt_h : Wkvt_h;
    const unsigned short* Wl = isq ? Wqt_l : Wkvt_l;
    const int m_blk  = blockIdx.x * 64;
    const int n_blk  = (isq ? by : by - 4) * 64;
    const int m_base = m_blk + (wv >> 1) * 32;
    const int n_gl   = n_blk + (wv & 1) * 32;    // col in W-space
    const int ar = (wv >> 1) * 32;
    const int wr = (wv & 1) * 32;

    // staging: thread t stages 8 elems (16B bf16 per array) per chunk
    const int srow = tid >> 2;             // 0..63
    const int skg  = (tid & 3) * 8;        // 0,8,16,24
    const size_t a_srcf = (size_t)(m_blk + srow) * 256 + skg;   // fp32 elems
    const size_t w_src  = (size_t)(n_blk + srow) * 256 + skg;   // bf16 elems
    const int sdst = srow * 40 + skg;

    const f4 fz = {0.f, 0.f, 0.f, 0.f};
    f4 acc[2][2] = {{fz, fz}, {fz, fz}};

    PMAIN_LOOP;

    if (blk_v) {
        // ---- V path: stage 64x64 tile in LDS, then write vT with slot perm
        #pragma unroll
        for (int mt = 0; mt < 2; ++mt)
            #pragma unroll
            for (int nt = 0; nt < 2; ++nt)
                #pragma unroll
                for (int r = 0; r < 4; ++r)
                    lt[(wv >> 1) * 32 + mt * 16 + grp * 4 + r]
                      [(wv & 1) * 32 + nt * 16 + col] = f2h(acc[mt][nt][r]);
        __syncthreads();
        const int dl  = tid & 63;             // d-col within block (0..63)
        const int q4  = tid >> 6;             // 16-key group (0..3)
        const int dgl = (by - 8) * 64 + dl;   // V d-space 0..255
        const int h   = (dgl >> 5) & 7;
        const int dh  = dgl & 31;
        const int b   = m_blk >> 12;
        const int l0  = m_blk & 4095;
        unsigned ow[8];
        #pragma unroll
        for (int i2 = 0; i2 < 8; ++i2) {
            unsigned lohi[2];
            #pragma unroll
            for (int e = 0; e < 2; ++e) {
                const int s  = q4 * 16 + i2 * 2 + e;     // slot within 64 keys
                const int ch = s >> 5;                    // 32-key chunk (0/1)
                const int ws = s & 31;
                const int kl = ch * 32 + ((ws >> 3) << 2) + (((ws & 7) >> 2) << 4) + (ws & 3);
                lohi[e] = lt[kl][dl];
            }
            ow[i2] = lohi[0] | (lohi[1] << 16);
        }
        unsigned short* dst = vT + ((size_t)((b * H + h) * D + dh)) * L + l0 + q4 * 16;
        uint4 u0 = {ow[0], ow[1], ow[2], ow[3]};
        uint4 u1 = {ow[4], ow[5], ow[6], ow[7]};
        *reinterpret_cast<uint4*>(dst)     = u0;
        *reinterpret_cast<uint4*>(dst + 8) = u1;
        return;
    }

    // ---- q/k path: fused l2-norm epilogue
    const int  h  = (n_gl >> 5) & 7;
    const float tl = isq ? temp[h] * LOG2E : 1.0f;   // exp2 fold
    unsigned short* dst = isq ? qf : kf;

    #pragma unroll
    for (int mt = 0; mt < 2; ++mt)
        #pragma unroll
        for (int r = 0; r < 4; ++r) {
            float t = acc[mt][0][r] * acc[mt][0][r] + acc[mt][1][r] * acc[mt][1][r];
            t += __shfl_xor(t, 1);
            t += __shfl_xor(t, 2);
            t += __shfl_xor(t, 4);
            t += __shfl_xor(t, 8);
            const float scale = tl / fmaxf(sqrtf(t), 1e-12f);
            const int row = m_base + mt * 16 + grp * 4 + r;
            const int bb = row >> 12, l = row & 4095;
            const size_t base = ((size_t)(bb * H + h) * L + l) * D;
            dst[base + col]      = f2h(acc[mt][0][r] * scale);
            dst[base + 16 + col] = f2h(acc[mt][1][r] * scale);
        }
}

// ---------------------------------------------------------------------------
// Output projection GEMM (LDS-staged, bf16-A), fp32 out.
// ---------------------------------------------------------------------------
__global__ __launch_bounds__(256) void gemm_mfma(
    const unsigned short* __restrict__ Ahp, const unsigned short* __restrict__ Alp,
    const unsigned short* __restrict__ Wth, const unsigned short* __restrict__ Wtl,
    float* __restrict__ out, int N) {
    GSTAGE_DECL
    const int tid  = threadIdx.x;
    const int wv   = tid >> 6;
    const int lane = tid & 63;
    const int col  = lane & 15;
    const int grp  = lane >> 4;
    const int m_blk  = blockIdx.x * 64;
    const int n_blk  = blockIdx.y * 64;
    const int m_base = m_blk + (wv >> 1) * 32;
    const int n_base = n_blk + (wv & 1) * 32;
    const int ar = (wv >> 1) * 32;
    const int wr = (wv & 1) * 32;

    const unsigned short* Ah = Ahp;
    const unsigned short* Al = Alp;
    const unsigned short* Wh = Wth;
    const unsigned short* Wl = Wtl;

    const int srow = tid >> 2;
    const int skg  = (tid & 3) * 8;
    const size_t a_src = (size_t)(m_blk + srow) * 256 + skg;
    const size_t w_src = (size_t)(n_blk + srow) * 256 + skg;
    const int sdst = srow * 40 + skg;

    const f4 fz = {0.f, 0.f, 0.f, 0.f};
    f4 acc[2][2] = {{fz, fz}, {fz, fz}};

    GMAIN_LOOP;

    #pragma unroll
    for (int mt = 0; mt < 2; ++mt)
        #pragma unroll
        for (int nt = 0; nt < 2; ++nt)
            #pragma unroll
            for (int r = 0; r < 4; ++r)
                out[(size_t)(m_base + mt * 16 + grp * 4 + r) * N + n_base + nt * 16 + col] =
                    acc[mt][nt][r];
}

// ---------------------------------------------------------------------------
// fp16 MFMA flash attention (r16: 4 q-tiles/wave, 2048 blocks, KSPLIT=8,
// XCD swizzle, hw exp2, LDS-staged double-buffered K/V chunks).
// ---------------------------------------------------------------------------
#define CHUNKL(CUR) do {                                                    \
    h8 kk0 = *reinterpret_cast<const h8*>(&sbuf[CUR][col * 32 + grp * 8]);  \
    h8 kk1 = *reinterpret_cast<const h8*>(&sbuf[CUR][(col + 16) * 32 + grp * 8]); \
    h8 vv0 = *reinterpret_cast<const h8*>(&sbuf[CUR][1024 + col * 32 + grp * 8]); \
    h8 vv1 = *reinterpret_cast<const h8*>(&sbuf[CUR][1024 + (col + 16) * 32 + grp * 8]); \
    _Pragma("unroll")                                                       \
    for (int qt = 0; qt < 4; ++qt) {                                        \
        f4 s0 = __builtin_amdgcn_mfma_f32_16x16x32_f16(kk0, qa[qt], fz, 0, 0, 0); \
        f4 s1 = __builtin_amdgcn_mfma_f32_16x16x32_f16(kk1, qa[qt], fz, 0, 0, 0); \
        float p[8];                                                         \
        _Pragma("unroll")                                                   \
        for (int r = 0; r < 4; ++r) {                                       \
            p[r]     = __builtin_amdgcn_exp2f(s0[r]);                       \
            p[r + 4] = __builtin_amdgcn_exp2f(s1[r]);                       \
        }                                                                   \
        ls[qt] += ((p[0] + p[1]) + (p[2] + p[3])) + ((p[4] + p[5]) + (p[6] + p[7])); \
        union { unsigned u[4]; h8 v; } pa;                                  \
        pa.u[0] = pkrtz(p[0], p[1]);                                        \
        pa.u[1] = pkrtz(p[2], p[3]);                                        \
        pa.u[2] = pkrtz(p[4], p[5]);                                        \
        pa.u[3] = pkrtz(p[6], p[7]);                                        \
        acc[qt][0] = __builtin_amdgcn_mfma_f32_16x16x32_f16(pa.v, vv0, acc[qt][0], 0, 0, 0); \
        acc[qt][1] = __builtin_amdgcn_mfma_f32_16x16x32_f16(pa.v, vv1, acc[qt][1], 0, 0, 0); \
    }                                                                       \
} while (0)

__global__ __launch_bounds__(256, 4) void attn_fp16(
    const unsigned short* __restrict__ qf, const unsigned short* __restrict__ kf,
    const unsigned short* __restrict__ vT,
    unsigned short* __restrict__ pacc,  // [KSPLIT][NQT][32] fp16
    float* __restrict__ pl) {           // [KSPLIT][NQT]
    // sbuf chunk layout: [0..1023] K (key-major [32 keys][32 d]),
    //                    [1024..2047] V (d-major [32 d][32 slots])
    __shared__ __align__(16) unsigned short sbuf[2][2048];

    // XCD-aware swizzle: XCD = bx%8; o contiguous per XCD; sp == XCD id
    const int o  = (blockIdx.x & 7) * 256 + (blockIdx.x >> 3);
    const int qb = o & 15;
    const int bh = (o >> 4) & 15;
    const int sp = o >> 8;
    const int tid  = threadIdx.x;
    const int wv   = tid >> 6;
    const int lane = tid & 63;
    const int col  = lane & 15;
    const int grp  = lane >> 4;

    const int q0 = qb * 256 + wv * 64;
    h8 qa[4];
    #pragma unroll
    for (int qt = 0; qt < 4; ++qt)
        qa[qt] = *reinterpret_cast<const h8*>(
            qf + ((size_t)bh * L + q0 + qt * 16 + col) * D + grp * 8);

    const f4 fz = {0.f, 0.f, 0.f, 0.f};
    f4 acc[4][2] = {{fz, fz}, {fz, fz}, {fz, fz}, {fz, fz}};
    float ls[4] = {};

    const int kstart = sp * (L / KSPLIT);
    constexpr int SPAN = L / KSPLIT;    // 512

    // per-thread staging source: wave 0/1 -> K slice, wave 2/3 -> V slice
    const unsigned short* gsb;
    size_t gmul;
    if (wv < 2) {
        gsb  = kf + (size_t)bh * L * D + (size_t)wv * 512 + (size_t)lane * 8;
        gmul = 32;
    } else {
        gsb  = vT + ((size_t)bh * D + (wv - 2) * 16 + (lane >> 2)) * L + (lane & 3) * 8;
        gmul = 1;
    }
    const int lidx = wv * 512 + lane * 8;

    #define LOADG(KIDX) (*reinterpret_cast<const uint4*>(gsb + (size_t)(KIDX) * gmul))

    uint4 t = LOADG(kstart);
    *reinterpret_cast<uint4*>(&sbuf[0][lidx]) = t;
    __syncthreads();
    for (int c = 0; c < SPAN; c += 64) {
        t = LOADG(kstart + c + 32);
        CHUNKL(0);
        *reinterpret_cast<uint4*>(&sbuf[1][lidx]) = t;
        __syncthreads();
        const int nx = (c + 64 < SPAN) ? (kstart + c + 64) : kstart;  // tail: dummy
        t = LOADG(nx);
        CHUNKL(1);
        *reinterpret_cast<uint4*>(&sbuf[0][lidx]) = t;
        __syncthreads();
    }
    #undef LOADG

    // denominators: reduce across the 4 grp groups (lane bits 4,5)
    #pragma unroll
    for (int qt = 0; qt < 4; ++qt) {
        ls[qt] += __shfl_xor(ls[qt], 16);
        ls[qt] += __shfl_xor(ls[qt], 32);
    }

    const size_t pbase = (size_t)sp * NQT + (size_t)bh * L;
    if (lane < 16) {
        #pragma unroll
        for (int qt = 0; qt < 4; ++qt)
            pl[pbase + q0 + qt * 16 + lane] = ls[qt];
    }
    #pragma unroll
    for (int qt = 0; qt < 4; ++qt)
        #pragma unroll
        for (int dt = 0; dt < 2; ++dt)
            #pragma unroll
            for (int r = 0; r < 4; ++r) {
                const int q = q0 + qt * 16 + grp * 4 + r;
                pacc[(pbase + q) * D + dt * 16 + col] = f2h(acc[qt][dt][r]);
            }
}

// ---------------------------------------------------------------------------
// Combine 8 key-splits, normalize, write bf16-split attnout (feeds Wo GEMM).
// ---------------------------------------------------------------------------
__global__ __launch_bounds__(256) void combine_split(
    const unsigned short* __restrict__ pacc, const float* __restrict__ pl,
    unsigned short* __restrict__ ah, unsigned short* __restrict__ al) {
    const int q = blockIdx.x * 256 + threadIdx.x;      // bh*L + l
    float den = 0.f;
    #pragma unroll
    for (int sp = 0; sp < KSPLIT; ++sp) den += pl[(size_t)sp * NQT + q];
    const float inv = 1.0f / den;

    float o[D] = {};
    #pragma unroll
    for (int sp = 0; sp < KSPLIT; ++sp) {
        const unsigned short* a = pacc + ((size_t)sp * NQT + q) * D;
        unsigned short t[D];
        #pragma unroll
        for (int i = 0; i < 4; ++i)
            *reinterpret_cast<uint4*>(&t[i * 8]) = *reinterpret_cast<const uint4*>(a + i * 8);
        #pragma unroll
        for (int d = 0; d < D; ++d) o[d] += h2f(t[d]);
    }

    const int bh = q >> 12, lq = q & 4095;
    const int b = bh >> 3, h = bh & 7;
    unsigned short oh[D], ol[D];
    #pragma unroll
    for (int d = 0; d < D; ++d) {
        float v = o[d] * inv;
        oh[d] = f2bf(v);
        ol[d] = f2bf(v - bf2f(oh[d]));
    }
    const size_t dst = ((size_t)(b * L + lq)) * C + h * D;
    #pragma unroll
    for (int i = 0; i < 4; ++i) {
        *reinterpret_cast<uint4*>(ah + dst + i * 8) = *reinterpret_cast<uint4*>(&oh[i * 8]);
        *reinterpret_cast<uint4*>(al + dst + i * 8) = *reinterpret_cast<uint4*>(&ol[i * 8]);
    }
}

// ---------------------------------------------------------------------------
extern "C" void kernel_launch(void* const* d_in, const int* in_sizes, int n_in,
                              void* d_out, int out_size, void* d_ws, size_t ws_size,
                              hipStream_t stream) {
    const float* x    = (const float*)d_in[0];
    const float* y    = (const float*)d_in[1];
    const float* Wq   = (const float*)d_in[2];
    const float* Wkv  = (const float*)d_in[3];
    const float* Wo   = (const float*)d_in[4];
    const float* temp = (const float*)d_in[5];
    float* out = (float*)d_out;

    // workspace layout (1 MB = 1048576 B), total 47 MB
    char* w = (char*)d_ws;
    constexpr size_t MB = 1048576;
    unsigned short* qf     = (unsigned short*)(w + 0 * MB);      // 4MB
    unsigned short* kf     = (unsigned short*)(w + 4 * MB);      // 4MB
    unsigned short* vT     = (unsigned short*)(w + 8 * MB);      // 4MB
    unsigned short* Wqt_h  = (unsigned short*)(w + 12 * MB);          // 128KB
    unsigned short* Wqt_l  = (unsigned short*)(w + 12 * MB + 131072);
    unsigned short* Wkvt_h = (unsigned short*)(w + 12 * MB + 262144); // 256KB
    unsigned short* Wkvt_l = (unsigned short*)(w + 12 * MB + 524288);
    unsigned short* Wot_h  = (unsigned short*)(w + 12 * MB + 786432); // 128KB
    unsigned short* Wot_l  = (unsigned short*)(w + 12 * MB + 917504);
    float*          pl     = (float*)(w + 13 * MB);              // 2MB [8][NQT]
    unsigned short* pacc   = (unsigned short*)(w + 15 * MB);     // 32MB [8][NQT][32]
    unsigned short* ahg    = qf;     // overlay (qf dead after attn)
    unsigned short* alg    = kf;

    // 1) weight transpose/split only (x/y split fused into gemm_proj)
    prep_w<<<1024, 256, 0, stream>>>(Wq, Wkv, Wo,
                                     Wqt_h, Wqt_l, Wkvt_h, Wkvt_l, Wot_h, Wot_l);

    // 2) merged projections (LDS-staged, fused x/y split): q/k norm -> qf/kf ; v -> vT
    gemm_proj<<<dim3(M / 64, 12), 256, 0, stream>>>(
        x, y, Wqt_h, Wqt_l, Wkvt_h, Wkvt_l, temp, qf, kf, vT);

    // 3) fp16 MFMA attention, KSPLIT=8, XCD swizzle, LDS-staged K/V chunks
    attn_fp16<<<2048, 256, 0, stream>>>(qf, kf, vT, pacc, pl);

    // 4) combine splits -> bf16-split attnout (overlays qf/kf)
    combine_split<<<NQT / 256, 256, 0, stream>>>(pacc, pl, ahg, alg);

    // 5) output projection (LDS-staged) -> d_out
    gemm_mfma<<<dim3(M / 64, C / 64), 256, 0, stream>>>(ahg, alg, Wot_h, Wot_l, out, C);
}

// Round 19
// 93.744 us; speedup vs baseline: 2.0930x; 1.0286x over previous
//
#include <hip/hip_runtime.h>
#include <math.h>

// Problem constants
constexpr int B  = 2;
constexpr int L  = 4096;
constexpr int C  = 256;
constexpr int H  = 8;
constexpr int D  = 32;          // head dim
constexpr int M  = B * L;       // 8192 rows
constexpr int BH = B * H;       // 16
constexpr int KSPLIT = 8;       // one key-split per XCD
constexpr int NQT = BH * L;     // 65536
constexpr float LOG2E = 1.4426950408889634f;

typedef short    s8 __attribute__((ext_vector_type(8)));   // 8 bf16
typedef _Float16 h8 __attribute__((ext_vector_type(8)));   // 8 fp16
typedef __fp16   hp2 __attribute__((ext_vector_type(2)));  // cvt_pkrtz native type
typedef float    f4 __attribute__((ext_vector_type(4)));   // MFMA C/D

__device__ __forceinline__ unsigned short f2bf(float x) {
    unsigned u = __float_as_uint(x);
    u += 0x7fffu + ((u >> 16) & 1u);      // RNE
    return (unsigned short)(u >> 16);
}
__device__ __forceinline__ float bf2f(unsigned short h) {
    return __uint_as_float(((unsigned)h) << 16);
}
__device__ __forceinline__ unsigned pkrtz(float a, float b) {
    union { hp2 h; unsigned u; } c;
    c.h = __builtin_amdgcn_cvt_pkrtz(a, b);   // v_cvt_pkrtz_f16_f32
    return c.u;
}
__device__ __forceinline__ unsigned short f2h(float x) {
    union { _Float16 h; unsigned short u; } c; c.h = (_Float16)x; return c.u;  // RNE
}
__device__ __forceinline__ float h2f(unsigned short u) {
    union { _Float16 h; unsigned short u; } c; c.u = u; return (float)c.h;
}

// ---------------------------------------------------------------------------
// Weights-only prep: transpose + bf16-split the 3 weight matrices.
// ---------------------------------------------------------------------------
__global__ __launch_bounds__(256) void prep_w(
    const float* __restrict__ Wq, const float* __restrict__ Wkv, const float* __restrict__ Wo,
    unsigned short* __restrict__ Wqt_h, unsigned short* __restrict__ Wqt_l,
    unsigned short* __restrict__ Wkvt_h, unsigned short* __restrict__ Wkvt_l,
    unsigned short* __restrict__ Wot_h, unsigned short* __restrict__ Wot_l) {
    const int t = blockIdx.x * 256 + threadIdx.x;   // 0..262143
    const float* W; unsigned short *Oh, *Ol; int nlog2, idx;
    if (t < 65536)       { W = Wq;  Oh = Wqt_h;  Ol = Wqt_l;  nlog2 = 8; idx = t; }
    else if (t < 196608) { W = Wkv; Oh = Wkvt_h; Ol = Wkvt_l; nlog2 = 9; idx = t - 65536; }
    else                 { W = Wo;  Oh = Wot_h;  Ol = Wot_l;  nlog2 = 8; idx = t - 196608; }
    const int NN = 1 << nlog2;
    const int n = idx & (NN - 1);
    const int k = idx >> nlog2;
    const float w = W[(size_t)k * NN + n];
    const unsigned short h = f2bf(w);
    Oh[(size_t)n * 256 + k] = h;
    Ol[(size_t)n * 256 + k] = f2bf(w - bf2f(h));
}

// ---------------------------------------------------------------------------
// Staged-GEMM building blocks. BK=32 chunks, double-buffered LDS
// [64 rows][40 elems] per array (row pad +8; 80B rows stay 16B-aligned).
// T14 order per chunk: global->reg loads for c+1, compute c, ds_write, barrier.
// ---------------------------------------------------------------------------
#define GSTAGE_DECL                                                         \
    __shared__ __align__(16) unsigned short sAh[2][2560], sAl[2][2560],     \
                                            sWh[2][2560], sWl[2][2560];

#define GCOMPUTE(BUF) do {                                                  \
    s8 ah[2], al[2], wh[2], wl[2];                                          \
    _Pragma("unroll")                                                       \
    for (int mt = 0; mt < 2; ++mt) {                                        \
        const int ai = (ar + mt * 16 + col) * 40 + grp * 8;                 \
        ah[mt] = *reinterpret_cast<const s8*>(&sAh[BUF][ai]);               \
        al[mt] = *reinterpret_cast<const s8*>(&sAl[BUF][ai]);               \
    }                                                                       \
    _Pragma("unroll")                                                       \
    for (int nt = 0; nt < 2; ++nt) {                                        \
        const int wi = (wr + nt * 16 + col) * 40 + grp * 8;                 \
        wh[nt] = *reinterpret_cast<const s8*>(&sWh[BUF][wi]);               \
        wl[nt] = *reinterpret_cast<const s8*>(&sWl[BUF][wi]);               \
    }                                                                       \
    _Pragma("unroll")                                                       \
    for (int mt = 0; mt < 2; ++mt)                                          \
        _Pragma("unroll")                                                   \
        for (int nt = 0; nt < 2; ++nt) {                                    \
            acc[mt][nt] = __builtin_amdgcn_mfma_f32_16x16x32_bf16(ah[mt], wh[nt], acc[mt][nt], 0, 0, 0); \
            acc[mt][nt] = __builtin_amdgcn_mfma_f32_16x16x32_bf16(al[mt], wh[nt], acc[mt][nt], 0, 0, 0); \
            acc[mt][nt] = __builtin_amdgcn_mfma_f32_16x16x32_bf16(ah[mt], wl[nt], acc[mt][nt], 0, 0, 0); \
        }                                                                   \
} while (0)

// --- bf16-A variant (gemm_mfma: Wo projection) ---
#define GSTAGE_LOAD(TA_H, TA_L, TW_H, TW_L, CI) do {                        \
    TA_H = *reinterpret_cast<const uint4*>(Ah + a_src + (CI) * 32);         \
    TA_L = *reinterpret_cast<const uint4*>(Al + a_src + (CI) * 32);         \
    TW_H = *reinterpret_cast<const uint4*>(Wh + w_src + (CI) * 32);         \
    TW_L = *reinterpret_cast<const uint4*>(Wl + w_src + (CI) * 32);         \
} while (0)

#define GSTAGE_WRITE(BUF, TA_H, TA_L, TW_H, TW_L) do {                      \
    *reinterpret_cast<uint4*>(&sAh[BUF][sdst]) = TA_H;                      \
    *reinterpret_cast<uint4*>(&sAl[BUF][sdst]) = TA_L;                      \
    *reinterpret_cast<uint4*>(&sWh[BUF][sdst]) = TW_H;                      \
    *reinterpret_cast<uint4*>(&sWl[BUF][sdst]) = TW_L;                      \
} while (0)

#define GMAIN_LOOP do {                                                     \
    uint4 tAh, tAl, tWh, tWl;                                               \
    GSTAGE_LOAD(tAh, tAl, tWh, tWl, 0);                                     \
    GSTAGE_WRITE(0, tAh, tAl, tWh, tWl);                                    \
    __syncthreads();                                                        \
    for (int c = 0; c < 8; c += 2) {                                        \
        if (c + 1 < 8) GSTAGE_LOAD(tAh, tAl, tWh, tWl, c + 1);              \
        GCOMPUTE(0);                                                        \
        if (c + 1 < 8) GSTAGE_WRITE(1, tAh, tAl, tWh, tWl);                 \
        __syncthreads();                                                    \
        if (c + 2 < 8) GSTAGE_LOAD(tAh, tAl, tWh, tWl, c + 2);              \
        if (c + 1 < 8) GCOMPUTE(1);                                         \
        if (c + 2 < 8) GSTAGE_WRITE(0, tAh, tAl, tWh, tWl);                 \
        __syncthreads();                                                    \
    }                                                                       \
} while (0)

// --- fp32-A variant (gemm_proj: reads raw x/y, splits during staging) ---
#define PSTAGE_LOAD(FA0, FA1, TW_H, TW_L, CI) do {                          \
    FA0 = *reinterpret_cast<const float4*>(Af + a_srcf + (CI) * 32);        \
    FA1 = *reinterpret_cast<const float4*>(Af + a_srcf + (CI) * 32 + 4);    \
    TW_H = *reinterpret_cast<const uint4*>(Wh + w_src + (CI) * 32);         \
    TW_L = *reinterpret_cast<const uint4*>(Wl + w_src + (CI) * 32);         \
} while (0)

#define PSTAGE_WRITE(BUF, FA0, FA1, TW_H, TW_L) do {                        \
    float vv[8];                                                            \
    *reinterpret_cast<float4*>(&vv[0]) = FA0;                               \
    *reinterpret_cast<float4*>(&vv[4]) = FA1;                               \
    unsigned short hs_[8], lo_[8];                                          \
    _Pragma("unroll")                                                       \
    for (int j = 0; j < 8; ++j) {                                           \
        hs_[j] = f2bf(vv[j]);                                               \
        lo_[j] = f2bf(vv[j] - bf2f(hs_[j]));                                \
    }                                                                       \
    *reinterpret_cast<uint4*>(&sAh[BUF][sdst]) = *reinterpret_cast<uint4*>(hs_); \
    *reinterpret_cast<uint4*>(&sAl[BUF][sdst]) = *reinterpret_cast<uint4*>(lo_); \
    *reinterpret_cast<uint4*>(&sWh[BUF][sdst]) = TW_H;                      \
    *reinterpret_cast<uint4*>(&sWl[BUF][sdst]) = TW_L;                      \
} while (0)

#define PMAIN_LOOP do {                                                     \
    float4 fa0, fa1; uint4 tWh, tWl;                                        \
    PSTAGE_LOAD(fa0, fa1, tWh, tWl, 0);                                     \
    PSTAGE_WRITE(0, fa0, fa1, tWh, tWl);                                    \
    __syncthreads();                                                        \
    for (int c = 0; c < 8; c += 2) {                                        \
        if (c + 1 < 8) PSTAGE_LOAD(fa0, fa1, tWh, tWl, c + 1);              \
        GCOMPUTE(0);                                                        \
        if (c + 1 < 8) PSTAGE_WRITE(1, fa0, fa1, tWh, tWl);                 \
        __syncthreads();                                                    \
        if (c + 2 < 8) PSTAGE_LOAD(fa0, fa1, tWh, tWl, c + 2);              \
        if (c + 1 < 8) GCOMPUTE(1);                                         \
        if (c + 2 < 8) PSTAGE_WRITE(0, fa0, fa1, tWh, tWl);                 \
        __syncthreads();                                                    \
    }                                                                       \
} while (0)

// ---------------------------------------------------------------------------
// MERGED projection: q (by 0..3), k (by 4..7), v (by 8..11). LDS-staged with
// FUSED fp32->bf16 hi/lo split of x/y during staging (no xh..yl buffers).
// q/k: fused l2-norm epilogue -> fp16 qf/kf [bh][l][32] (q: temp*LOG2E fold).
// v:   fused transpose+perm epilogue -> fp16 vT[bh][d][slot] directly.
// ---------------------------------------------------------------------------
__global__ __launch_bounds__(256) void gemm_proj(
    const float* __restrict__ x, const float* __restrict__ y,
    const unsigned short* __restrict__ Wqt_h, const unsigned short* __restrict__ Wqt_l,
    const unsigned short* __restrict__ Wkvt_h, const unsigned short* __restrict__ Wkvt_l,
    const float* __restrict__ temp,
    unsigned short* __restrict__ qf, unsigned short* __restrict__ kf,
    unsigned short* __restrict__ vT) {
    GSTAGE_DECL
    __shared__ unsigned short lt[64][68];   // v-transpose buffer (8.5KB)
    const int tid  = threadIdx.x;
    const int wv   = tid >> 6;
    const int lane = tid & 63;
    const int col  = lane & 15;
    const int grp  = lane >> 4;
    const int by   = blockIdx.y;
    const bool isq   = (by < 4);
    const bool blk_v = (by >= 8);
    const float* Af = isq ? x : y;
    const unsigned short* Wh = isq ? Wqt_h : Wkvt_h;
    const unsigned short* Wl = isq ? Wqt_l : Wkvt_l;
    const int m_blk  = blockIdx.x * 64;
    const int n_blk  = (isq ? by : by - 4) * 64;
    const int m_base = m_blk + (wv >> 1) * 32;
    const int n_gl   = n_blk + (wv & 1) * 32;    // col in W-space
    const int ar = (wv >> 1) * 32;
    const int wr = (wv & 1) * 32;

    // staging: thread t stages 8 elems (16B bf16 per array) per chunk
    const int srow = tid >> 2;             // 0..63
    const int skg  = (tid & 3) * 8;        // 0,8,16,24
    const size_t a_srcf = (size_t)(m_blk + srow) * 256 + skg;   // fp32 elems
    const size_t w_src  = (size_t)(n_blk + srow) * 256 + skg;   // bf16 elems
    const int sdst = srow * 40 + skg;

    const f4 fz = {0.f, 0.f, 0.f, 0.f};
    f4 acc[2][2] = {{fz, fz}, {fz, fz}};

    PMAIN_LOOP;

    if (blk_v) {
        // ---- V path: stage 64x64 tile in LDS, then write vT with slot perm
        #pragma unroll
        for (int mt = 0; mt < 2; ++mt)
            #pragma unroll
            for (int nt = 0; nt < 2; ++nt)
                #pragma unroll
                for (int r = 0; r < 4; ++r)
                    lt[(wv >> 1) * 32 + mt * 16 + grp * 4 + r]
                      [(wv & 1) * 32 + nt * 16 + col] = f2h(acc[mt][nt][r]);
        __syncthreads();
        const int dl  = tid & 63;             // d-col within block (0..63)
        const int q4  = tid >> 6;             // 16-key group (0..3)
        const int dgl = (by - 8) * 64 + dl;   // V d-space 0..255
        const int h   = (dgl >> 5) & 7;
        const int dh  = dgl & 31;
        const int b   = m_blk >> 12;
        const int l0  = m_blk & 4095;
        unsigned ow[8];
        #pragma unroll
        for (int i2 = 0; i2 < 8; ++i2) {
            unsigned lohi[2];
            #pragma unroll
            for (int e = 0; e < 2; ++e) {
                const int s  = q4 * 16 + i2 * 2 + e;     // slot within 64 keys
                const int ch = s >> 5;                    // 32-key chunk (0/1)
                const int ws = s & 31;
                const int kl = ch * 32 + ((ws >> 3) << 2) + (((ws & 7) >> 2) << 4) + (ws & 3);
                lohi[e] = lt[kl][dl];
            }
            ow[i2] = lohi[0] | (lohi[1] << 16);
        }
        unsigned short* dst = vT + ((size_t)((b * H + h) * D + dh)) * L + l0 + q4 * 16;
        uint4 u0 = {ow[0], ow[1], ow[2], ow[3]};
        uint4 u1 = {ow[4], ow[5], ow[6], ow[7]};
        *reinterpret_cast<uint4*>(dst)     = u0;
        *reinterpret_cast<uint4*>(dst + 8) = u1;
        return;
    }

    // ---- q/k path: fused l2-norm epilogue
    const int  h  = (n_gl >> 5) & 7;
    const float tl = isq ? temp[h] * LOG2E : 1.0f;   // exp2 fold
    unsigned short* dst = isq ? qf : kf;

    #pragma unroll
    for (int mt = 0; mt < 2; ++mt)
        #pragma unroll
        for (int r = 0; r < 4; ++r) {
            float t = acc[mt][0][r] * acc[mt][0][r] + acc[mt][1][r] * acc[mt][1][r];
            t += __shfl_xor(t, 1);
            t += __shfl_xor(t, 2);
            t += __shfl_xor(t, 4);
            t += __shfl_xor(t, 8);
            const float scale = tl / fmaxf(sqrtf(t), 1e-12f);
            const int row = m_base + mt * 16 + grp * 4 + r;
            const int bb = row >> 12, l = row & 4095;
            const size_t base = ((size_t)(bb * H + h) * L + l) * D;
            dst[base + col]      = f2h(acc[mt][0][r] * scale);
            dst[base + 16 + col] = f2h(acc[mt][1][r] * scale);
        }
}

// ---------------------------------------------------------------------------
// Output projection GEMM (LDS-staged, bf16-A), fp32 out.
// ---------------------------------------------------------------------------
__global__ __launch_bounds__(256) void gemm_mfma(
    const unsigned short* __restrict__ Ahp, const unsigned short* __restrict__ Alp,
    const unsigned short* __restrict__ Wth, const unsigned short* __restrict__ Wtl,
    float* __restrict__ out, int N) {
    GSTAGE_DECL
    const int tid  = threadIdx.x;
    const int wv   = tid >> 6;
    const int lane = tid & 63;
    const int col  = lane & 15;
    const int grp  = lane >> 4;
    const int m_blk  = blockIdx.x * 64;
    const int n_blk  = blockIdx.y * 64;
    const int m_base = m_blk + (wv >> 1) * 32;
    const int n_base = n_blk + (wv & 1) * 32;
    const int ar = (wv >> 1) * 32;
    const int wr = (wv & 1) * 32;

    const unsigned short* Ah = Ahp;
    const unsigned short* Al = Alp;
    const unsigned short* Wh = Wth;
    const unsigned short* Wl = Wtl;

    const int srow = tid >> 2;
    const int skg  = (tid & 3) * 8;
    const size_t a_src = (size_t)(m_blk + srow) * 256 + skg;
    const size_t w_src = (size_t)(n_blk + srow) * 256 + skg;
    const int sdst = srow * 40 + skg;

    const f4 fz = {0.f, 0.f, 0.f, 0.f};
    f4 acc[2][2] = {{fz, fz}, {fz, fz}};

    GMAIN_LOOP;

    #pragma unroll
    for (int mt = 0; mt < 2; ++mt)
        #pragma unroll
        for (int nt = 0; nt < 2; ++nt)
            #pragma unroll
            for (int r = 0; r < 4; ++r)
                out[(size_t)(m_base + mt * 16 + grp * 4 + r) * N + n_base + nt * 16 + col] =
                    acc[mt][nt][r];
}

// ---------------------------------------------------------------------------
// fp16 MFMA flash attention (r16: 4 q-tiles/wave, 2048 blocks, KSPLIT=8,
// XCD swizzle, hw exp2, LDS-staged double-buffered K/V chunks).
// ---------------------------------------------------------------------------
#define CHUNKL(CUR) do {                                                    \
    h8 kk0 = *reinterpret_cast<const h8*>(&sbuf[CUR][col * 32 + grp * 8]);  \
    h8 kk1 = *reinterpret_cast<const h8*>(&sbuf[CUR][(col + 16) * 32 + grp * 8]); \
    h8 vv0 = *reinterpret_cast<const h8*>(&sbuf[CUR][1024 + col * 32 + grp * 8]); \
    h8 vv1 = *reinterpret_cast<const h8*>(&sbuf[CUR][1024 + (col + 16) * 32 + grp * 8]); \
    _Pragma("unroll")                                                       \
    for (int qt = 0; qt < 4; ++qt) {                                        \
        f4 s0 = __builtin_amdgcn_mfma_f32_16x16x32_f16(kk0, qa[qt], fz, 0, 0, 0); \
        f4 s1 = __builtin_amdgcn_mfma_f32_16x16x32_f16(kk1, qa[qt], fz, 0, 0, 0); \
        float p[8];                                                         \
        _Pragma("unroll")                                                   \
        for (int r = 0; r < 4; ++r) {                                       \
            p[r]     = __builtin_amdgcn_exp2f(s0[r]);                       \
            p[r + 4] = __builtin_amdgcn_exp2f(s1[r]);                       \
        }                                                                   \
        ls[qt] += ((p[0] + p[1]) + (p[2] + p[3])) + ((p[4] + p[5]) + (p[6] + p[7])); \
        union { unsigned u[4]; h8 v; } pa;                                  \
        pa.u[0] = pkrtz(p[0], p[1]);                                        \
        pa.u[1] = pkrtz(p[2], p[3]);                                        \
        pa.u[2] = pkrtz(p[4], p[5]);                                        \
        pa.u[3] = pkrtz(p[6], p[7]);                                        \
        acc[qt][0] = __builtin_amdgcn_mfma_f32_16x16x32_f16(pa.v, vv0, acc[qt][0], 0, 0, 0); \
        acc[qt][1] = __builtin_amdgcn_mfma_f32_16x16x32_f16(pa.v, vv1, acc[qt][1], 0, 0, 0); \
    }                                                                       \
} while (0)

__global__ __launch_bounds__(256, 4) void attn_fp16(
    const unsigned short* __restrict__ qf, const unsigned short* __restrict__ kf,
    const unsigned short* __restrict__ vT,
    unsigned short* __restrict__ pacc,  // [KSPLIT][NQT][32] fp16
    float* __restrict__ pl) {           // [KSPLIT][NQT]
    // sbuf chunk layout: [0..1023] K (key-major [32 keys][32 d]),
    //                    [1024..2047] V (d-major [32 d][32 slots])
    __shared__ __align__(16) unsigned short sbuf[2][2048];

    // XCD-aware swizzle: XCD = bx%8; o contiguous per XCD; sp == XCD id
    const int o  = (blockIdx.x & 7) * 256 + (blockIdx.x >> 3);
    const int qb = o & 15;
    const int bh = (o >> 4) & 15;
    const int sp = o >> 8;
    const int tid  = threadIdx.x;
    const int wv   = tid >> 6;
    const int lane = tid & 63;
    const int col  = lane & 15;
    const int grp  = lane >> 4;

    const int q0 = qb * 256 + wv * 64;
    h8 qa[4];
    #pragma unroll
    for (int qt = 0; qt < 4; ++qt)
        qa[qt] = *reinterpret_cast<const h8*>(
            qf + ((size_t)bh * L + q0 + qt * 16 + col) * D + grp * 8);

    const f4 fz = {0.f, 0.f, 0.f, 0.f};
    f4 acc[4][2] = {{fz, fz}, {fz, fz}, {fz, fz}, {fz, fz}};
    float ls[4] = {};

    const int kstart = sp * (L / KSPLIT);
    constexpr int SPAN = L / KSPLIT;    // 512

    // per-thread staging source: wave 0/1 -> K slice, wave 2/3 -> V slice
    const unsigned short* gsb;
    size_t gmul;
    if (wv < 2) {
        gsb  = kf + (size_t)bh * L * D + (size_t)wv * 512 + (size_t)lane * 8;
        gmul = 32;
    } else {
        gsb  = vT + ((size_t)bh * D + (wv - 2) * 16 + (lane >> 2)) * L + (lane & 3) * 8;
        gmul = 1;
    }
    const int lidx = wv * 512 + lane * 8;

    #define LOADG(KIDX) (*reinterpret_cast<const uint4*>(gsb + (size_t)(KIDX) * gmul))

    uint4 t = LOADG(kstart);
    *reinterpret_cast<uint4*>(&sbuf[0][lidx]) = t;
    __syncthreads();
    for (int c = 0; c < SPAN; c += 64) {
        t = LOADG(kstart + c + 32);
        CHUNKL(0);
        *reinterpret_cast<uint4*>(&sbuf[1][lidx]) = t;
        __syncthreads();
        const int nx = (c + 64 < SPAN) ? (kstart + c + 64) : kstart;  // tail: dummy
        t = LOADG(nx);
        CHUNKL(1);
        *reinterpret_cast<uint4*>(&sbuf[0][lidx]) = t;
        __syncthreads();
    }
    #undef LOADG

    // denominators: reduce across the 4 grp groups (lane bits 4,5)
    #pragma unroll
    for (int qt = 0; qt < 4; ++qt) {
        ls[qt] += __shfl_xor(ls[qt], 16);
        ls[qt] += __shfl_xor(ls[qt], 32);
    }

    const size_t pbase = (size_t)sp * NQT + (size_t)bh * L;
    if (lane < 16) {
        #pragma unroll
        for (int qt = 0; qt < 4; ++qt)
            pl[pbase + q0 + qt * 16 + lane] = ls[qt];
    }
    #pragma unroll
    for (int qt = 0; qt < 4; ++qt)
        #pragma unroll
        for (int dt = 0; dt < 2; ++dt)
            #pragma unroll
            for (int r = 0; r < 4; ++r) {
                const int q = q0 + qt * 16 + grp * 4 + r;
                pacc[(pbase + q) * D + dt * 16 + col] = f2h(acc[qt][dt][r]);
            }
}

// ---------------------------------------------------------------------------
// Combine 8 key-splits, normalize, write bf16-split attnout (feeds Wo GEMM).
// 4 threads per q (one per 8-elem d-slice) -> 1024 blocks for TLP/BW.
// Per-d summation order identical to previous version (sp ascending).
// ---------------------------------------------------------------------------
__global__ __launch_bounds__(256) void combine_split(
    const unsigned short* __restrict__ pacc, const float* __restrict__ pl,
    unsigned short* __restrict__ ah, unsigned short* __restrict__ al) {
    const int idx = blockIdx.x * 256 + threadIdx.x;    // 0..262143
    const int q = idx >> 2;                            // bh*L + l
    const int dpart = (idx & 3) * 8;                   // 0,8,16,24

    float den = 0.f;
    #pragma unroll
    for (int sp = 0; sp < KSPLIT; ++sp) den += pl[(size_t)sp * NQT + q];
    const float inv = 1.0f / den;

    float o[8] = {};
    #pragma unroll
    for (int sp = 0; sp < KSPLIT; ++sp) {
        unsigned short t[8];
        *reinterpret_cast<uint4*>(t) = *reinterpret_cast<const uint4*>(
            pacc + ((size_t)sp * NQT + q) * D + dpart);
        #pragma unroll
        for (int d = 0; d < 8; ++d) o[d] += h2f(t[d]);
    }

    const int bh = q >> 12, lq = q & 4095;
    const int b = bh >> 3, h = bh & 7;
    unsigned short oh[8], ol[8];
    #pragma unroll
    for (int d = 0; d < 8; ++d) {
        float v = o[d] * inv;
        oh[d] = f2bf(v);
        ol[d] = f2bf(v - bf2f(oh[d]));
    }
    const size_t dst = ((size_t)(b * L + lq)) * C + h * D + dpart;
    *reinterpret_cast<uint4*>(ah + dst) = *reinterpret_cast<uint4*>(oh);
    *reinterpret_cast<uint4*>(al + dst) = *reinterpret_cast<uint4*>(ol);
}

// ---------------------------------------------------------------------------
extern "C" void kernel_launch(void* const* d_in, const int* in_sizes, int n_in,
                              void* d_out, int out_size, void* d_ws, size_t ws_size,
                              hipStream_t stream) {
    const float* x    = (const float*)d_in[0];
    const float* y    = (const float*)d_in[1];
    const float* Wq   = (const float*)d_in[2];
    const float* Wkv  = (const float*)d_in[3];
    const float* Wo   = (const float*)d_in[4];
    const float* temp = (const float*)d_in[5];
    float* out = (float*)d_out;

    // workspace layout (1 MB = 1048576 B), total 47 MB
    char* w = (char*)d_ws;
    constexpr size_t MB = 1048576;
    unsigned short* qf     = (unsigned short*)(w + 0 * MB);      // 4MB
    unsigned short* kf     = (unsigned short*)(w + 4 * MB);      // 4MB
    unsigned short* vT     = (unsigned short*)(w + 8 * MB);      // 4MB
    unsigned short* Wqt_h  = (unsigned short*)(w + 12 * MB);          // 128KB
    unsigned short* Wqt_l  = (unsigned short*)(w + 12 * MB + 131072);
    unsigned short* Wkvt_h = (unsigned short*)(w + 12 * MB + 262144); // 256KB
    unsigned short* Wkvt_l = (unsigned short*)(w + 12 * MB + 524288);
    unsigned short* Wot_h  = (unsigned short*)(w + 12 * MB + 786432); // 128KB
    unsigned short* Wot_l  = (unsigned short*)(w + 12 * MB + 917504);
    float*          pl     = (float*)(w + 13 * MB);              // 2MB [8][NQT]
    unsigned short* pacc   = (unsigned short*)(w + 15 * MB);     // 32MB [8][NQT][32]
    unsigned short* ahg    = qf;     // overlay (qf dead after attn)
    unsigned short* alg    = kf;

    // 1) weight transpose/split only (x/y split fused into gemm_proj)
    prep_w<<<1024, 256, 0, stream>>>(Wq, Wkv, Wo,
                                     Wqt_h, Wqt_l, Wkvt_h, Wkvt_l, Wot_h, Wot_l);

    // 2) merged projections (LDS-staged, fused x/y split): q/k norm -> qf/kf ; v -> vT
    gemm_proj<<<dim3(M / 64, 12), 256, 0, stream>>>(
        x, y, Wqt_h, Wqt_l, Wkvt_h, Wkvt_l, temp, qf, kf, vT);

    // 3) fp16 MFMA attention, KSPLIT=8, XCD swizzle, LDS-staged K/V chunks
    attn_fp16<<<2048, 256, 0, stream>>>(qf, kf, vT, pacc, pl);

    // 4) combine splits (4 threads/q) -> bf16-split attnout (overlays qf/kf)
    combine_split<<<(NQT * 4) / 256, 256, 0, stream>>>(pacc, pl, ahg, alg);

    // 5) output projection (LDS-staged) -> d_out
    gemm_mfma<<<dim3(M / 64, C / 64), 256, 0, stream>>>(ahg, alg, Wot_h, Wot_l, out, C);
}

// Round 20
// 92.091 us; speedup vs baseline: 2.1306x; 1.0179x over previous
//
#include <hip/hip_runtime.h>
#include <math.h>

// Problem constants
constexpr int B  = 2;
constexpr int L  = 4096;
constexpr int C  = 256;
constexpr int H  = 8;
constexpr int D  = 32;          // head dim
constexpr int M  = B * L;       // 8192 rows
constexpr int BH = B * H;       // 16
constexpr int KSPLIT = 4;       // 1024 blocks; attn is issue-bound now
constexpr int NQT = BH * L;     // 65536
constexpr float LOG2E = 1.4426950408889634f;

typedef short    s8 __attribute__((ext_vector_type(8)));   // 8 bf16
typedef _Float16 h8 __attribute__((ext_vector_type(8)));   // 8 fp16
typedef __fp16   hp2 __attribute__((ext_vector_type(2)));  // cvt_pkrtz native type
typedef float    f4 __attribute__((ext_vector_type(4)));   // MFMA C/D

__device__ __forceinline__ unsigned short f2bf(float x) {
    unsigned u = __float_as_uint(x);
    u += 0x7fffu + ((u >> 16) & 1u);      // RNE
    return (unsigned short)(u >> 16);
}
__device__ __forceinline__ float bf2f(unsigned short h) {
    return __uint_as_float(((unsigned)h) << 16);
}
__device__ __forceinline__ unsigned pkrtz(float a, float b) {
    union { hp2 h; unsigned u; } c;
    c.h = __builtin_amdgcn_cvt_pkrtz(a, b);   // v_cvt_pkrtz_f16_f32
    return c.u;
}
__device__ __forceinline__ unsigned short f2h(float x) {
    union { _Float16 h; unsigned short u; } c; c.h = (_Float16)x; return c.u;  // RNE
}
__device__ __forceinline__ float h2f(unsigned short u) {
    union { _Float16 h; unsigned short u; } c; c.u = u; return (float)c.h;
}

// ---------------------------------------------------------------------------
// Weights-only prep: transpose + bf16-split the 3 weight matrices.
// ---------------------------------------------------------------------------
__global__ __launch_bounds__(256) void prep_w(
    const float* __restrict__ Wq, const float* __restrict__ Wkv, const float* __restrict__ Wo,
    unsigned short* __restrict__ Wqt_h, unsigned short* __restrict__ Wqt_l,
    unsigned short* __restrict__ Wkvt_h, unsigned short* __restrict__ Wkvt_l,
    unsigned short* __restrict__ Wot_h, unsigned short* __restrict__ Wot_l) {
    const int t = blockIdx.x * 256 + threadIdx.x;   // 0..262143
    const float* W; unsigned short *Oh, *Ol; int nlog2, idx;
    if (t < 65536)       { W = Wq;  Oh = Wqt_h;  Ol = Wqt_l;  nlog2 = 8; idx = t; }
    else if (t < 196608) { W = Wkv; Oh = Wkvt_h; Ol = Wkvt_l; nlog2 = 9; idx = t - 65536; }
    else                 { W = Wo;  Oh = Wot_h;  Ol = Wot_l;  nlog2 = 8; idx = t - 196608; }
    const int NN = 1 << nlog2;
    const int n = idx & (NN - 1);
    const int k = idx >> nlog2;
    const float w = W[(size_t)k * NN + n];
    const unsigned short h = f2bf(w);
    Oh[(size_t)n * 256 + k] = h;
    Ol[(size_t)n * 256 + k] = f2bf(w - bf2f(h));
}

// ---------------------------------------------------------------------------
// Staged-GEMM building blocks. BK=32 chunks, double-buffered LDS
// [64 rows][40 elems] per array (row pad +8; 80B rows stay 16B-aligned).
// T14 order per chunk: global->reg loads for c+1, compute c, ds_write, barrier.
// ---------------------------------------------------------------------------
#define GSTAGE_DECL                                                         \
    __shared__ __align__(16) unsigned short sAh[2][2560], sAl[2][2560],     \
                                            sWh[2][2560], sWl[2][2560];

#define GCOMPUTE(BUF) do {                                                  \
    s8 ah[2], al[2], wh[2], wl[2];                                          \
    _Pragma("unroll")                                                       \
    for (int mt = 0; mt < 2; ++mt) {                                        \
        const int ai = (ar + mt * 16 + col) * 40 + grp * 8;                 \
        ah[mt] = *reinterpret_cast<const s8*>(&sAh[BUF][ai]);               \
        al[mt] = *reinterpret_cast<const s8*>(&sAl[BUF][ai]);               \
    }                                                                       \
    _Pragma("unroll")                                                       \
    for (int nt = 0; nt < 2; ++nt) {                                        \
        const int wi = (wr + nt * 16 + col) * 40 + grp * 8;                 \
        wh[nt] = *reinterpret_cast<const s8*>(&sWh[BUF][wi]);               \
        wl[nt] = *reinterpret_cast<const s8*>(&sWl[BUF][wi]);               \
    }                                                                       \
    _Pragma("unroll")                                                       \
    for (int mt = 0; mt < 2; ++mt)                                          \
        _Pragma("unroll")                                                   \
        for (int nt = 0; nt < 2; ++nt) {                                    \
            acc[mt][nt] = __builtin_amdgcn_mfma_f32_16x16x32_bf16(ah[mt], wh[nt], acc[mt][nt], 0, 0, 0); \
            acc[mt][nt] = __builtin_amdgcn_mfma_f32_16x16x32_bf16(al[mt], wh[nt], acc[mt][nt], 0, 0, 0); \
            acc[mt][nt] = __builtin_amdgcn_mfma_f32_16x16x32_bf16(ah[mt], wl[nt], acc[mt][nt], 0, 0, 0); \
        }                                                                   \
} while (0)

// --- bf16-A variant (gemm_mfma: Wo projection) ---
#define GSTAGE_LOAD(TA_H, TA_L, TW_H, TW_L, CI) do {                        \
    TA_H = *reinterpret_cast<const uint4*>(Ah + a_src + (CI) * 32);         \
    TA_L = *reinterpret_cast<const uint4*>(Al + a_src + (CI) * 32);         \
    TW_H = *reinterpret_cast<const uint4*>(Wh + w_src + (CI) * 32);         \
    TW_L = *reinterpret_cast<const uint4*>(Wl + w_src + (CI) * 32);         \
} while (0)

#define GSTAGE_WRITE(BUF, TA_H, TA_L, TW_H, TW_L) do {                      \
    *reinterpret_cast<uint4*>(&sAh[BUF][sdst]) = TA_H;                      \
    *reinterpret_cast<uint4*>(&sAl[BUF][sdst]) = TA_L;                      \
    *reinterpret_cast<uint4*>(&sWh[BUF][sdst]) = TW_H;                      \
    *reinterpret_cast<uint4*>(&sWl[BUF][sdst]) = TW_L;                      \
} while (0)

#define GMAIN_LOOP do {                                                     \
    uint4 tAh, tAl, tWh, tWl;                                               \
    GSTAGE_LOAD(tAh, tAl, tWh, tWl, 0);                                     \
    GSTAGE_WRITE(0, tAh, tAl, tWh, tWl);                                    \
    __syncthreads();                                                        \
    for (int c = 0; c < 8; c += 2) {                                        \
        if (c + 1 < 8) GSTAGE_LOAD(tAh, tAl, tWh, tWl, c + 1);              \
        GCOMPUTE(0);                                                        \
        if (c + 1 < 8) GSTAGE_WRITE(1, tAh, tAl, tWh, tWl);                 \
        __syncthreads();                                                    \
        if (c + 2 < 8) GSTAGE_LOAD(tAh, tAl, tWh, tWl, c + 2);              \
        if (c + 1 < 8) GCOMPUTE(1);                                         \
        if (c + 2 < 8) GSTAGE_WRITE(0, tAh, tAl, tWh, tWl);                 \
        __syncthreads();                                                    \
    }                                                                       \
} while (0)

// --- fp32-A variant (gemm_proj: reads raw x/y, splits during staging) ---
#define PSTAGE_LOAD(FA0, FA1, TW_H, TW_L, CI) do {                          \
    FA0 = *reinterpret_cast<const float4*>(Af + a_srcf + (CI) * 32);        \
    FA1 = *reinterpret_cast<const float4*>(Af + a_srcf + (CI) * 32 + 4);    \
    TW_H = *reinterpret_cast<const uint4*>(Wh + w_src + (CI) * 32);         \
    TW_L = *reinterpret_cast<const uint4*>(Wl + w_src + (CI) * 32);         \
} while (0)

#define PSTAGE_WRITE(BUF, FA0, FA1, TW_H, TW_L) do {                        \
    float vv[8];                                                            \
    *reinterpret_cast<float4*>(&vv[0]) = FA0;                               \
    *reinterpret_cast<float4*>(&vv[4]) = FA1;                               \
    unsigned short hs_[8], lo_[8];                                          \
    _Pragma("unroll")                                                       \
    for (int j = 0; j < 8; ++j) {                                           \
        hs_[j] = f2bf(vv[j]);                                               \
        lo_[j] = f2bf(vv[j] - bf2f(hs_[j]));                                \
    }                                                                       \
    *reinterpret_cast<uint4*>(&sAh[BUF][sdst]) = *reinterpret_cast<uint4*>(hs_); \
    *reinterpret_cast<uint4*>(&sAl[BUF][sdst]) = *reinterpret_cast<uint4*>(lo_); \
    *reinterpret_cast<uint4*>(&sWh[BUF][sdst]) = TW_H;                      \
    *reinterpret_cast<uint4*>(&sWl[BUF][sdst]) = TW_L;                      \
} while (0)

#define PMAIN_LOOP do {                                                     \
    float4 fa0, fa1; uint4 tWh, tWl;                                        \
    PSTAGE_LOAD(fa0, fa1, tWh, tWl, 0);                                     \
    PSTAGE_WRITE(0, fa0, fa1, tWh, tWl);                                    \
    __syncthreads();                                                        \
    for (int c = 0; c < 8; c += 2) {                                        \
        if (c + 1 < 8) PSTAGE_LOAD(fa0, fa1, tWh, tWl, c + 1);              \
        GCOMPUTE(0);                                                        \
        if (c + 1 < 8) PSTAGE_WRITE(1, fa0, fa1, tWh, tWl);                 \
        __syncthreads();                                                    \
        if (c + 2 < 8) PSTAGE_LOAD(fa0, fa1, tWh, tWl, c + 2);              \
        if (c + 1 < 8) GCOMPUTE(1);                                         \
        if (c + 2 < 8) PSTAGE_WRITE(0, fa0, fa1, tWh, tWl);                 \
        __syncthreads();                                                    \
    }                                                                       \
} while (0)

// ---------------------------------------------------------------------------
// MERGED projection: q (by 0..3), k (by 4..7), v (by 8..11). LDS-staged with
// FUSED fp32->bf16 hi/lo split of x/y during staging.
// q/k: fused l2-norm epilogue -> fp16 qf/kf [bh][l][32] (q: temp*LOG2E fold).
// v:   fused transpose+perm epilogue -> fp16 vT[bh][d][slot] directly.
// ---------------------------------------------------------------------------
__global__ __launch_bounds__(256) void gemm_proj(
    const float* __restrict__ x, const float* __restrict__ y,
    const unsigned short* __restrict__ Wqt_h, const unsigned short* __restrict__ Wqt_l,
    const unsigned short* __restrict__ Wkvt_h, const unsigned short* __restrict__ Wkvt_l,
    const float* __restrict__ temp,
    unsigned short* __restrict__ qf, unsigned short* __restrict__ kf,
    unsigned short* __restrict__ vT) {
    GSTAGE_DECL
    __shared__ unsigned short lt[64][68];   // v-transpose buffer (8.5KB)
    const int tid  = threadIdx.x;
    const int wv   = tid >> 6;
    const int lane = tid & 63;
    const int col  = lane & 15;
    const int grp  = lane >> 4;
    const int by   = blockIdx.y;
    const bool isq   = (by < 4);
    const bool blk_v = (by >= 8);
    const float* Af = isq ? x : y;
    const unsigned short* Wh = isq ? Wqt_h : Wkvt_h;
    const unsigned short* Wl = isq ? Wqt_l : Wkvt_l;
    const int m_blk  = blockIdx.x * 64;
    const int n_blk  = (isq ? by : by - 4) * 64;
    const int m_base = m_blk + (wv >> 1) * 32;
    const int n_gl   = n_blk + (wv & 1) * 32;    // col in W-space
    const int ar = (wv >> 1) * 32;
    const int wr = (wv & 1) * 32;

    const int srow = tid >> 2;             // 0..63
    const int skg  = (tid & 3) * 8;        // 0,8,16,24
    const size_t a_srcf = (size_t)(m_blk + srow) * 256 + skg;   // fp32 elems
    const size_t w_src  = (size_t)(n_blk + srow) * 256 + skg;   // bf16 elems
    const int sdst = srow * 40 + skg;

    const f4 fz = {0.f, 0.f, 0.f, 0.f};
    f4 acc[2][2] = {{fz, fz}, {fz, fz}};

    PMAIN_LOOP;

    if (blk_v) {
        // ---- V path: stage 64x64 tile in LDS, then write vT with slot perm
        #pragma unroll
        for (int mt = 0; mt < 2; ++mt)
            #pragma unroll
            for (int nt = 0; nt < 2; ++nt)
                #pragma unroll
                for (int r = 0; r < 4; ++r)
                    lt[(wv >> 1) * 32 + mt * 16 + grp * 4 + r]
                      [(wv & 1) * 32 + nt * 16 + col] = f2h(acc[mt][nt][r]);
        __syncthreads();
        const int dl  = tid & 63;             // d-col within block (0..63)
        const int q4  = tid >> 6;             // 16-key group (0..3)
        const int dgl = (by - 8) * 64 + dl;   // V d-space 0..255
        const int h   = (dgl >> 5) & 7;
        const int dh  = dgl & 31;
        const int b   = m_blk >> 12;
        const int l0  = m_blk & 4095;
        unsigned ow[8];
        #pragma unroll
        for (int i2 = 0; i2 < 8; ++i2) {
            unsigned lohi[2];
            #pragma unroll
            for (int e = 0; e < 2; ++e) {
                const int s  = q4 * 16 + i2 * 2 + e;     // slot within 64 keys
                const int ch = s >> 5;                    // 32-key chunk (0/1)
                const int ws = s & 31;
                const int kl = ch * 32 + ((ws >> 3) << 2) + (((ws & 7) >> 2) << 4) + (ws & 3);
                lohi[e] = lt[kl][dl];
            }
            ow[i2] = lohi[0] | (lohi[1] << 16);
        }
        unsigned short* dst = vT + ((size_t)((b * H + h) * D + dh)) * L + l0 + q4 * 16;
        uint4 u0 = {ow[0], ow[1], ow[2], ow[3]};
        uint4 u1 = {ow[4], ow[5], ow[6], ow[7]};
        *reinterpret_cast<uint4*>(dst)     = u0;
        *reinterpret_cast<uint4*>(dst + 8) = u1;
        return;
    }

    // ---- q/k path: fused l2-norm epilogue
    const int  h  = (n_gl >> 5) & 7;
    const float tl = isq ? temp[h] * LOG2E : 1.0f;   // exp2 fold
    unsigned short* dst = isq ? qf : kf;

    #pragma unroll
    for (int mt = 0; mt < 2; ++mt)
        #pragma unroll
        for (int r = 0; r < 4; ++r) {
            float t = acc[mt][0][r] * acc[mt][0][r] + acc[mt][1][r] * acc[mt][1][r];
            t += __shfl_xor(t, 1);
            t += __shfl_xor(t, 2);
            t += __shfl_xor(t, 4);
            t += __shfl_xor(t, 8);
            const float scale = tl / fmaxf(sqrtf(t), 1e-12f);
            const int row = m_base + mt * 16 + grp * 4 + r;
            const int bb = row >> 12, l = row & 4095;
            const size_t base = ((size_t)(bb * H + h) * L + l) * D;
            dst[base + col]      = f2h(acc[mt][0][r] * scale);
            dst[base + 16 + col] = f2h(acc[mt][1][r] * scale);
        }
}

// ---------------------------------------------------------------------------
// Output projection GEMM (LDS-staged, bf16-A), fp32 out.
// ---------------------------------------------------------------------------
__global__ __launch_bounds__(256) void gemm_mfma(
    const unsigned short* __restrict__ Ahp, const unsigned short* __restrict__ Alp,
    const unsigned short* __restrict__ Wth, const unsigned short* __restrict__ Wtl,
    float* __restrict__ out, int N) {
    GSTAGE_DECL
    const int tid  = threadIdx.x;
    const int wv   = tid >> 6;
    const int lane = tid & 63;
    const int col  = lane & 15;
    const int grp  = lane >> 4;
    const int m_blk  = blockIdx.x * 64;
    const int n_blk  = blockIdx.y * 64;
    const int m_base = m_blk + (wv >> 1) * 32;
    const int n_base = n_blk + (wv & 1) * 32;
    const int ar = (wv >> 1) * 32;
    const int wr = (wv & 1) * 32;

    const unsigned short* Ah = Ahp;
    const unsigned short* Al = Alp;
    const unsigned short* Wh = Wth;
    const unsigned short* Wl = Wtl;

    const int srow = tid >> 2;
    const int skg  = (tid & 3) * 8;
    const size_t a_src = (size_t)(m_blk + srow) * 256 + skg;
    const size_t w_src = (size_t)(n_blk + srow) * 256 + skg;
    const int sdst = srow * 40 + skg;

    const f4 fz = {0.f, 0.f, 0.f, 0.f};
    f4 acc[2][2] = {{fz, fz}, {fz, fz}};

    GMAIN_LOOP;

    #pragma unroll
    for (int mt = 0; mt < 2; ++mt)
        #pragma unroll
        for (int nt = 0; nt < 2; ++nt)
            #pragma unroll
            for (int r = 0; r < 4; ++r)
                out[(size_t)(m_base + mt * 16 + grp * 4 + r) * N + n_base + nt * 16 + col] =
                    acc[mt][nt][r];
}

// ---------------------------------------------------------------------------
// fp16 MFMA flash attention (4 q-tiles/wave, KSPLIT=4 -> 1024 blocks, XCD
// swizzle, hw exp2, LDS-staged double-buffered K/V chunks). Issue-bound:
// fewer blocks OK; halves pacc traffic vs KSPLIT=8.
// ---------------------------------------------------------------------------
#define CHUNKL(CUR) do {                                                    \
    h8 kk0 = *reinterpret_cast<const h8*>(&sbuf[CUR][col * 32 + grp * 8]);  \
    h8 kk1 = *reinterpret_cast<const h8*>(&sbuf[CUR][(col + 16) * 32 + grp * 8]); \
    h8 vv0 = *reinterpret_cast<const h8*>(&sbuf[CUR][1024 + col * 32 + grp * 8]); \
    h8 vv1 = *reinterpret_cast<const h8*>(&sbuf[CUR][1024 + (col + 16) * 32 + grp * 8]); \
    _Pragma("unroll")                                                       \
    for (int qt = 0; qt < 4; ++qt) {                                        \
        f4 s0 = __builtin_amdgcn_mfma_f32_16x16x32_f16(kk0, qa[qt], fz, 0, 0, 0); \
        f4 s1 = __builtin_amdgcn_mfma_f32_16x16x32_f16(kk1, qa[qt], fz, 0, 0, 0); \
        float p[8];                                                         \
        _Pragma("unroll")                                                   \
        for (int r = 0; r < 4; ++r) {                                       \
            p[r]     = __builtin_amdgcn_exp2f(s0[r]);                       \
            p[r + 4] = __builtin_amdgcn_exp2f(s1[r]);                       \
        }                                                                   \
        ls[qt] += ((p[0] + p[1]) + (p[2] + p[3])) + ((p[4] + p[5]) + (p[6] + p[7])); \
        union { unsigned u[4]; h8 v; } pa;                                  \
        pa.u[0] = pkrtz(p[0], p[1]);                                        \
        pa.u[1] = pkrtz(p[2], p[3]);                                        \
        pa.u[2] = pkrtz(p[4], p[5]);                                        \
        pa.u[3] = pkrtz(p[6], p[7]);                                        \
        acc[qt][0] = __builtin_amdgcn_mfma_f32_16x16x32_f16(pa.v, vv0, acc[qt][0], 0, 0, 0); \
        acc[qt][1] = __builtin_amdgcn_mfma_f32_16x16x32_f16(pa.v, vv1, acc[qt][1], 0, 0, 0); \
    }                                                                       \
} while (0)

__global__ __launch_bounds__(256, 4) void attn_fp16(
    const unsigned short* __restrict__ qf, const unsigned short* __restrict__ kf,
    const unsigned short* __restrict__ vT,
    unsigned short* __restrict__ pacc,  // [KSPLIT][NQT][32] fp16
    float* __restrict__ pl) {           // [KSPLIT][NQT]
    // sbuf chunk layout: [0..1023] K (key-major), [1024..2047] V (d-major)
    __shared__ __align__(16) unsigned short sbuf[2][2048];

    // XCD-aware swizzle: XCD = bx%8; o contiguous per XCD (1024 blocks)
    const int o  = (blockIdx.x & 7) * 128 + (blockIdx.x >> 3);
    const int qb = o & 15;
    const int bh = (o >> 4) & 15;
    const int sp = o >> 8;              // 0..3
    const int tid  = threadIdx.x;
    const int wv   = tid >> 6;
    const int lane = tid & 63;
    const int col  = lane & 15;
    const int grp  = lane >> 4;

    const int q0 = qb * 256 + wv * 64;
    h8 qa[4];
    #pragma unroll
    for (int qt = 0; qt < 4; ++qt)
        qa[qt] = *reinterpret_cast<const h8*>(
            qf + ((size_t)bh * L + q0 + qt * 16 + col) * D + grp * 8);

    const f4 fz = {0.f, 0.f, 0.f, 0.f};
    f4 acc[4][2] = {{fz, fz}, {fz, fz}, {fz, fz}, {fz, fz}};
    float ls[4] = {};

    const int kstart = sp * (L / KSPLIT);
    constexpr int SPAN = L / KSPLIT;    // 1024 -> 32 chunks

    // per-thread staging source: wave 0/1 -> K slice, wave 2/3 -> V slice
    const unsigned short* gsb;
    size_t gmul;
    if (wv < 2) {
        gsb  = kf + (size_t)bh * L * D + (size_t)wv * 512 + (size_t)lane * 8;
        gmul = 32;
    } else {
        gsb  = vT + ((size_t)bh * D + (wv - 2) * 16 + (lane >> 2)) * L + (lane & 3) * 8;
        gmul = 1;
    }
    const int lidx = wv * 512 + lane * 8;

    #define LOADG(KIDX) (*reinterpret_cast<const uint4*>(gsb + (size_t)(KIDX) * gmul))

    uint4 t = LOADG(kstart);
    *reinterpret_cast<uint4*>(&sbuf[0][lidx]) = t;
    __syncthreads();
    for (int c = 0; c < SPAN; c += 64) {
        t = LOADG(kstart + c + 32);
        CHUNKL(0);
        *reinterpret_cast<uint4*>(&sbuf[1][lidx]) = t;
        __syncthreads();
        const int nx = (c + 64 < SPAN) ? (kstart + c + 64) : kstart;  // tail: dummy
        t = LOADG(nx);
        CHUNKL(1);
        *reinterpret_cast<uint4*>(&sbuf[0][lidx]) = t;
        __syncthreads();
    }
    #undef LOADG

    // denominators: reduce across the 4 grp groups (lane bits 4,5)
    #pragma unroll
    for (int qt = 0; qt < 4; ++qt) {
        ls[qt] += __shfl_xor(ls[qt], 16);
        ls[qt] += __shfl_xor(ls[qt], 32);
    }

    const size_t pbase = (size_t)sp * NQT + (size_t)bh * L;
    if (lane < 16) {
        #pragma unroll
        for (int qt = 0; qt < 4; ++qt)
            pl[pbase + q0 + qt * 16 + lane] = ls[qt];
    }
    #pragma unroll
    for (int qt = 0; qt < 4; ++qt)
        #pragma unroll
        for (int dt = 0; dt < 2; ++dt)
            #pragma unroll
            for (int r = 0; r < 4; ++r) {
                const int q = q0 + qt * 16 + grp * 4 + r;
                pacc[(pbase + q) * D + dt * 16 + col] = f2h(acc[qt][dt][r]);
            }
}

// ---------------------------------------------------------------------------
// Combine 4 key-splits, normalize, write bf16-split attnout (feeds Wo GEMM).
// 4 threads per q (one per 8-elem d-slice) -> 1024 blocks for TLP/BW.
// ---------------------------------------------------------------------------
__global__ __launch_bounds__(256) void combine_split(
    const unsigned short* __restrict__ pacc, const float* __restrict__ pl,
    unsigned short* __restrict__ ah, unsigned short* __restrict__ al) {
    const int idx = blockIdx.x * 256 + threadIdx.x;    // 0..262143
    const int q = idx >> 2;                            // bh*L + l
    const int dpart = (idx & 3) * 8;                   // 0,8,16,24

    float den = 0.f;
    #pragma unroll
    for (int sp = 0; sp < KSPLIT; ++sp) den += pl[(size_t)sp * NQT + q];
    const float inv = 1.0f / den;

    float o[8] = {};
    #pragma unroll
    for (int sp = 0; sp < KSPLIT; ++sp) {
        unsigned short t[8];
        *reinterpret_cast<uint4*>(t) = *reinterpret_cast<const uint4*>(
            pacc + ((size_t)sp * NQT + q) * D + dpart);
        #pragma unroll
        for (int d = 0; d < 8; ++d) o[d] += h2f(t[d]);
    }

    const int bh = q >> 12, lq = q & 4095;
    const int b = bh >> 3, h = bh & 7;
    unsigned short oh[8], ol[8];
    #pragma unroll
    for (int d = 0; d < 8; ++d) {
        float v = o[d] * inv;
        oh[d] = f2bf(v);
        ol[d] = f2bf(v - bf2f(oh[d]));
    }
    const size_t dst = ((size_t)(b * L + lq)) * C + h * D + dpart;
    *reinterpret_cast<uint4*>(ah + dst) = *reinterpret_cast<uint4*>(oh);
    *reinterpret_cast<uint4*>(al + dst) = *reinterpret_cast<uint4*>(ol);
}

// ---------------------------------------------------------------------------
extern "C" void kernel_launch(void* const* d_in, const int* in_sizes, int n_in,
                              void* d_out, int out_size, void* d_ws, size_t ws_size,
                              hipStream_t stream) {
    const float* x    = (const float*)d_in[0];
    const float* y    = (const float*)d_in[1];
    const float* Wq   = (const float*)d_in[2];
    const float* Wkv  = (const float*)d_in[3];
    const float* Wo   = (const float*)d_in[4];
    const float* temp = (const float*)d_in[5];
    float* out = (float*)d_out;

    // workspace layout (1 MB = 1048576 B), total 31 MB
    char* w = (char*)d_ws;
    constexpr size_t MB = 1048576;
    unsigned short* qf     = (unsigned short*)(w + 0 * MB);      // 4MB
    unsigned short* kf     = (unsigned short*)(w + 4 * MB);      // 4MB
    unsigned short* vT     = (unsigned short*)(w + 8 * MB);      // 4MB
    unsigned short* Wqt_h  = (unsigned short*)(w + 12 * MB);          // 128KB
    unsigned short* Wqt_l  = (unsigned short*)(w + 12 * MB + 131072);
    unsigned short* Wkvt_h = (unsigned short*)(w + 12 * MB + 262144); // 256KB
    unsigned short* Wkvt_l = (unsigned short*)(w + 12 * MB + 524288);
    unsigned short* Wot_h  = (unsigned short*)(w + 12 * MB + 786432); // 128KB
    unsigned short* Wot_l  = (unsigned short*)(w + 12 * MB + 917504);
    float*          pl     = (float*)(w + 13 * MB);              // 1MB [4][NQT]
    unsigned short* pacc   = (unsigned short*)(w + 15 * MB);     // 16MB [4][NQT][32]
    unsigned short* ahg    = qf;     // overlay (qf dead after attn)
    unsigned short* alg    = kf;

    // 1) weight transpose/split only (x/y split fused into gemm_proj)
    prep_w<<<1024, 256, 0, stream>>>(Wq, Wkv, Wo,
                                     Wqt_h, Wqt_l, Wkvt_h, Wkvt_l, Wot_h, Wot_l);

    // 2) merged projections (LDS-staged, fused x/y split): q/k norm -> qf/kf ; v -> vT
    gemm_proj<<<dim3(M / 64, 12), 256, 0, stream>>>(
        x, y, Wqt_h, Wqt_l, Wkvt_h, Wkvt_l, temp, qf, kf, vT);

    // 3) fp16 MFMA attention, KSPLIT=4, XCD swizzle, LDS-staged K/V chunks
    attn_fp16<<<1024, 256, 0, stream>>>(qf, kf, vT, pacc, pl);

    // 4) combine splits (4 threads/q) -> bf16-split attnout (overlays qf/kf)
    combine_split<<<(NQT * 4) / 256, 256, 0, stream>>>(pacc, pl, ahg, alg);

    // 5) output projection (LDS-staged) -> d_out
    gemm_mfma<<<dim3(M / 64, C / 64), 256, 0, stream>>>(ahg, alg, Wot_h, Wot_l, out, C);
}